// Round 3
// baseline (4993.006 us; speedup 1.0000x reference)
//
#include <hip/hip_runtime.h>
#include <hip/hip_bf16.h>

#define B 128
#define T 64
#define E 512
#define H 512
#define AA 512
#define V 10000
#define NPAD 10112   // 79*128

typedef __hip_bfloat16 bf16;
typedef unsigned long long u64;
typedef __attribute__((ext_vector_type(8))) short bf16x8s;
typedef __attribute__((ext_vector_type(4))) short s16x4;
typedef __attribute__((ext_vector_type(4))) float f32x4;

#define MFMA __builtin_amdgcn_mfma_f32_16x16x32_bf16

__device__ __forceinline__ bf16x8s ld8(const bf16* p) {
  return *reinterpret_cast<const bf16x8s*>(p);
}
__device__ __forceinline__ float sigm(float x) { return 1.f / (1.f + __expf(-x)); }
__device__ __forceinline__ float bf2f(unsigned short u) {
  return __uint_as_float(((unsigned)u) << 16);
}

// ---- coherent (agent-scope, fence-free) helpers: bypass non-coherent L1/L2 ----
__device__ __forceinline__ u64 aload(const void* p) {
  return __hip_atomic_load((const u64*)p, __ATOMIC_RELAXED, __HIP_MEMORY_SCOPE_AGENT);
}
__device__ __forceinline__ void astore(void* p, u64 v) {
  __hip_atomic_store((u64*)p, v, __ATOMIC_RELAXED, __HIP_MEMORY_SCOPE_AGENT);
}
__device__ __forceinline__ float aloadf(const float* p) {
  return __hip_atomic_load(p, __ATOMIC_RELAXED, __HIP_MEMORY_SCOPE_AGENT);
}
__device__ __forceinline__ bf16x8s ld8c(const bf16* p) {
  union { u64 v[2]; bf16x8s s; } u;
  u.v[0] = aload(p);
  u.v[1] = aload(p + 4);
  return u.s;
}

// ---------------- grid barrier (32 co-resident blocks, NO cache-flushing fences) ----------------
// Safe because: all cross-block data moves via agent-scope atomics (coherent point),
// and __syncthreads drains vmcnt(0) per wave before s_barrier, so data stores are
// globally visible before thread 0's arrive-add.
__device__ __forceinline__ void gbar(int* cnt, int target) {
  __syncthreads();
  if (threadIdx.x == 0) {
    __hip_atomic_fetch_add(cnt, 1, __ATOMIC_RELAXED, __HIP_MEMORY_SCOPE_AGENT);
    while (__hip_atomic_load(cnt, __ATOMIC_RELAXED, __HIP_MEMORY_SCOPE_AGENT) < target)
      __builtin_amdgcn_s_sleep(4);
  }
  __syncthreads();
}

// ---------------- prep kernels ----------------

__global__ __launch_bounds__(256) void kxs(const float* __restrict__ feat,
                                           const int* __restrict__ cap,
                                           const float* __restrict__ embW,
                                           bf16* __restrict__ xs) {
  int idx = blockIdx.x * 256 + threadIdx.x;   // B*T*E/4
  int e4 = (idx & 127) << 2;
  int b = (idx >> 7) & 127;
  int t = idx >> 14;
  const float* src = (t == 0) ? (feat + (size_t)b * E)
                              : (embW + (size_t)cap[b * (T - 1) + (t - 1)] * E);
  float4 v = *reinterpret_cast<const float4*>(src + e4);
  bf16* d = xs + ((size_t)t * B + b) * E + e4;
  d[0] = __float2bfloat16(v.x); d[1] = __float2bfloat16(v.y);
  d[2] = __float2bfloat16(v.z); d[3] = __float2bfloat16(v.w);
}

__global__ __launch_bounds__(256) void kcast(const float* __restrict__ s,
                                             bf16* __restrict__ d, int n4) {
  int i = blockIdx.x * 256 + threadIdx.x;
  if (i >= n4) return;
  float4 v = *reinterpret_cast<const float4*>(s + (size_t)i * 4);
  d[i * 4 + 0] = __float2bfloat16(v.x); d[i * 4 + 1] = __float2bfloat16(v.y);
  d[i * 4 + 2] = __float2bfloat16(v.z); d[i * 4 + 3] = __float2bfloat16(v.w);
}

// slice-cast: dst[r][0:512] = src[r][c0:c0+512], src ld=1024, R=512
__global__ __launch_bounds__(256) void kslice(const float* __restrict__ src,
                                              bf16* __restrict__ dst, int c0) {
  int i = blockIdx.x * 256 + threadIdx.x;   // 512*128
  int row = i >> 7, c4 = (i & 127) << 2;
  float4 v = *reinterpret_cast<const float4*>(src + (size_t)row * 1024 + c0 + c4);
  bf16* d = dst + (size_t)row * 512 + c4;
  d[0] = __float2bfloat16(v.x); d[1] = __float2bfloat16(v.y);
  d[2] = __float2bfloat16(v.z); d[3] = __float2bfloat16(v.w);
}

// transpose-cast: dst[a][e2] = src[e2][coff+a]; src (512 x ld1024)
__global__ __launch_bounds__(256) void ktrans(const float* __restrict__ src,
                                              bf16* __restrict__ dst, int coff) {
  __shared__ float tl[32][33];
  int bx = blockIdx.x & 15, by = blockIdx.x >> 4;
  int tx = threadIdx.x & 31, ty = threadIdx.x >> 5;
  for (int yy = ty; yy < 32; yy += 8)
    tl[yy][tx] = src[(size_t)(by * 32 + yy) * 1024 + coff + bx * 32 + tx];
  __syncthreads();
  for (int yy = ty; yy < 32; yy += 8)
    dst[(size_t)(bx * 32 + yy) * 512 + by * 32 + tx] = __float2bfloat16(tl[tx][yy]);
}

__global__ __launch_bounds__(256) void kpadW(const float* __restrict__ s,
                                             bf16* __restrict__ d) {
  int i = blockIdx.x * 256 + threadIdx.x;   // NPAD*H/4
  int row = (i << 2) / H;
  float4 v = make_float4(0.f, 0.f, 0.f, 0.f);
  if (row < V) v = *reinterpret_cast<const float4*>(s + (size_t)i * 4);
  d[i * 4 + 0] = __float2bfloat16(v.x); d[i * 4 + 1] = __float2bfloat16(v.y);
  d[i * 4 + 2] = __float2bfloat16(v.z); d[i * 4 + 3] = __float2bfloat16(v.w);
}

// gb0 = b_ih+b_hh ; gbA = gb0 + W_ih @ attd_b
__global__ __launch_bounds__(256) void kgb(const float* __restrict__ bih,
                                           const float* __restrict__ bhh,
                                           const float* __restrict__ Wih_f,
                                           const float* __restrict__ attdb,
                                           float* __restrict__ gb0,
                                           float* __restrict__ gbA) {
  int g = blockIdx.x * 256 + threadIdx.x;
  if (g >= 2048) return;
  float b0 = bih[g] + bhh[g];
  float s = 0.f;
  for (int e = 0; e < 512; ++e) s += Wih_f[(size_t)g * 512 + e] * attdb[e];
  gb0[g] = b0; gbA[g] = b0 + s;
}

// ---------------- m97-style GEMM: C[M,N] = A[M,512] @ Bw[N,512]^T ----------------
// EPI 0: fp32 out (stride V), +bias, masked by t<len, col<V
// EPI 1: bf16 out (stride Nld), +bias if non-null
template<int EPI>
__global__ __launch_bounds__(256) void kgemm(const bf16* __restrict__ Ag,
                                             const bf16* __restrict__ Bg,
                                             const float* __restrict__ bias,
                                             const int* __restrict__ len,
                                             float* __restrict__ outF,
                                             bf16* __restrict__ outB,
                                             int nbn, int Nld) {
  __shared__ __align__(16) char lds[2][2][16384];   // [buf][A/B][128 rows x 64 bf16]
  const int nwg = gridDim.x;
  const int bid0 = blockIdx.x;
  const int wg = (bid0 & 7) * (nwg >> 3) + (bid0 >> 3);   // XCD swizzle (nwg % 8 == 0)
  const int bm = wg / nbn, bn = wg % nbn;
  const int tid = threadIdx.x, w = tid >> 6, lane = tid & 63;
  const int fr = lane & 15, fq = lane >> 4, ko = fq << 3;
  const int mh = w >> 1, nh = w & 1;
  const bf16* Abase = Ag + (size_t)bm * 128 * 512;
  const bf16* Bbase = Bg + (size_t)bn * 128 * 512;

  f32x4 acc[4][4] = {};

  auto STAGE = [&](int buf, int k0) {
    #pragma unroll
    for (int it = 0; it < 4; ++it) {
      int si = tid + it * 256;
      int row = si >> 3;
      int s = (si & 7) ^ (row & 7);
      __builtin_amdgcn_global_load_lds(
        (const __attribute__((address_space(1))) void*)(Abase + (size_t)row * 512 + k0 + s * 8),
        (__attribute__((address_space(3))) void*)(&lds[buf][0][((tid & ~63) + it * 256) * 16]),
        16, 0, 0);
    }
    #pragma unroll
    for (int it = 0; it < 4; ++it) {
      int si = tid + it * 256;
      int row = si >> 3;
      int s = (si & 7) ^ (row & 7);
      __builtin_amdgcn_global_load_lds(
        (const __attribute__((address_space(1))) void*)(Bbase + (size_t)row * 512 + k0 + s * 8),
        (__attribute__((address_space(3))) void*)(&lds[buf][1][((tid & ~63) + it * 256) * 16]),
        16, 0, 0);
    }
  };

  STAGE(0, 0);
  __syncthreads();
  for (int kt = 0; kt < 8; ++kt) {
    int cur = kt & 1;
    if (kt < 7) STAGE(cur ^ 1, (kt + 1) * 64);
    #pragma unroll
    for (int kk = 0; kk < 64; kk += 32) {
      bf16x8s a[4], b[4];
      #pragma unroll
      for (int i = 0; i < 4; ++i) {
        int ra = mh * 64 + i * 16 + fr;
        a[i] = *reinterpret_cast<const bf16x8s*>(
            &lds[cur][0][ra * 128 + ((((kk + ko) >> 3) ^ (ra & 7)) << 4)]);
        int rb = nh * 64 + i * 16 + fr;
        b[i] = *reinterpret_cast<const bf16x8s*>(
            &lds[cur][1][rb * 128 + ((((kk + ko) >> 3) ^ (rb & 7)) << 4)]);
      }
      #pragma unroll
      for (int mi = 0; mi < 4; ++mi)
        #pragma unroll
        for (int ni = 0; ni < 4; ++ni)
          acc[mi][ni] = MFMA(a[mi], b[ni], acc[mi][ni], 0, 0, 0);
    }
    __syncthreads();
  }

  #pragma unroll
  for (int mi = 0; mi < 4; ++mi)
    #pragma unroll
    for (int ni = 0; ni < 4; ++ni)
      #pragma unroll
      for (int j = 0; j < 4; ++j) {
        int row = bm * 128 + mh * 64 + mi * 16 + fq * 4 + j;
        int col = bn * 128 + nh * 64 + ni * 16 + fr;
        if (EPI == 0) {
          if (col < V) {
            int tt = row >> 7, bb = row & 127;
            outF[(size_t)row * V + col] = (tt < len[bb]) ? acc[mi][ni][j] + bias[col] : 0.f;
          }
        } else {
          float bv = bias ? bias[col] : 0.f;
          outB[(size_t)row * Nld + col] = __float2bfloat16(acc[mi][ni][j] + bv);
        }
      }
}

// ---------------- persistent sequential loop ----------------
// 32 blocks x 512 threads. Per step t>=1:
//   gbar; phase1: S_h=h@WaH^T (+Sx) -> P'=exp*cnn, Z; gbar; phase2: gates=Gx+(P'@Kc^T)/Z+h@Whh^T+gb -> cell
// Cross-block data (h, P', Z) via agent-scope atomics only; weights stay plain/cached.
__global__ __launch_bounds__(512, 1) void kloop(
    const bf16* __restrict__ Sxb,    // [T][B][512]
    const bf16* __restrict__ Gx,     // [T][B][2048]
    const bf16* __restrict__ Kc,     // [2048][512]
    const bf16* __restrict__ Whh,    // [2048][512]
    const bf16* __restrict__ WaH,    // [512][512]
    const float* __restrict__ gb0,
    const float* __restrict__ gbA,
    const float* __restrict__ cnn,   // [B][512] f32
    const int* __restrict__ len,
    bf16* __restrict__ h0,
    bf16* __restrict__ h1,
    float* __restrict__ cst,         // [B][512]
    bf16* __restrict__ pbuf,         // [B][512]
    float* __restrict__ Zbuf,        // [T][B]
    bf16* __restrict__ hid,          // [T][B][512]
    int* __restrict__ cnt) {
  __shared__ float smem[8704];       // p1: [8][32][33]  p2: [4][64][34]
  const int tid = threadIdx.x, w = tid >> 6, lane = tid & 63;
  const int fr = lane & 15, fq = lane >> 4, ko = fq << 3;
  const int bid = blockIdx.x;
  // phase1: block = (m: 4x32 rows) x (n: 8x64 cols); wave = (ntile, kquarter)
  const int p1m = (bid & 3) << 5;
  const int p1n = (bid >> 2) << 6;
  const int p1nt = w & 1, p1kq = w >> 1;
  // phase2: block = (m: 2x64 rows) x (j: 16x32 h-cols); wave = (quarter, nhalf)
  const int p2m = (bid & 1) << 6;
  const int p2j = (bid >> 1) << 5;
  const int p2q = w >> 1, p2nh = w & 1;
  const int gc0 = p2q * 512 + p2j + p2nh * 16;

  int ep = 0;
  for (int t = 0; t < T; ++t) {
    const bf16* hin = (t & 1) ? h1 : h0;
    bf16* hout = (t & 1) ? h0 : h1;
    if (t) {
      gbar(cnt, 32 * (++ep));        // h ready
      // ---- phase 1 ----
      {
        f32x4 acc[2][2] = {};
        const bf16* ha = hin + (size_t)(p1m + fr) * H + p1kq * 128 + ko;
        const bf16* wb = WaH + (size_t)(p1n + p1nt * 32 + fr) * H + p1kq * 128 + ko;
        #pragma unroll
        for (int k = 0; k < 128; k += 32) {
          bf16x8s a0 = ld8c(ha + k), a1 = ld8c(ha + 16 * H + k);
          bf16x8s b0 = ld8(wb + k), b1 = ld8(wb + 16 * H + k);
          acc[0][0] = MFMA(a0, b0, acc[0][0], 0, 0, 0);
          acc[0][1] = MFMA(a0, b1, acc[0][1], 0, 0, 0);
          acc[1][0] = MFMA(a1, b0, acc[1][0], 0, 0, 0);
          acc[1][1] = MFMA(a1, b1, acc[1][1], 0, 0, 0);
        }
        #pragma unroll
        for (int mi = 0; mi < 2; ++mi)
          #pragma unroll
          for (int ni = 0; ni < 2; ++ni)
            #pragma unroll
            for (int j = 0; j < 4; ++j)
              smem[w * 1056 + (mi * 16 + fq * 4 + j) * 33 + ni * 16 + fr] = acc[mi][ni][j];
      }
      __syncthreads();
      {
        int nt2 = tid >> 8, idx = tid & 255;
        int rw = idx >> 3, c0 = (idx & 7) << 2;
        int grow = p1m + rw;
        int gcol = p1n + nt2 * 32 + c0;
        s16x4 sx = *reinterpret_cast<const s16x4*>(Sxb + ((size_t)t * B + grow) * AA + gcol);
        float4 cv = *reinterpret_cast<const float4*>(cnn + (size_t)grow * AA + gcol);
        const float* cvp = reinterpret_cast<const float*>(&cv);
        float z = 0.f;
        union { s16x4 s; u64 v; } pv;
        #pragma unroll
        for (int c = 0; c < 4; ++c) {
          float s = 0.f;
          #pragma unroll
          for (int kq = 0; kq < 4; ++kq)
            s += smem[(kq * 2 + nt2) * 1056 + rw * 33 + c0 + c];
          float p = __expf(s + bf2f((unsigned short)sx[c]));
          z += p;
          bf16 pb = __float2bfloat16(p * cvp[c]);
          pv.s[c] = *reinterpret_cast<const short*>(&pb);
        }
        astore(pbuf + (size_t)grow * AA + gcol, pv.v);
        z += __shfl_down(z, 4); z += __shfl_down(z, 2); z += __shfl_down(z, 1);
        if ((idx & 7) == 0) atomicAdd(Zbuf + t * B + grow, z);
      }
      gbar(cnt, 32 * (++ep));        // P', Z ready
    }
    // ---- phase 2 ----
    f32x4 acc[4] = {};
    if (t) {
      const bf16* pa = pbuf + (size_t)(p2m + fr) * AA + ko;
      const bf16* kb = Kc + (size_t)(gc0 + fr) * AA + ko;
      #pragma unroll 4
      for (int k = 0; k < 512; k += 32) {
        bf16x8s bv = ld8(kb + k);
        #pragma unroll
        for (int mi = 0; mi < 4; ++mi)
          acc[mi] = MFMA(ld8c(pa + mi * 16 * AA + k), bv, acc[mi], 0, 0, 0);
      }
      #pragma unroll
      for (int mi = 0; mi < 4; ++mi)
        #pragma unroll
        for (int j = 0; j < 4; ++j)
          acc[mi][j] *= __fdividef(1.f, aloadf(Zbuf + t * B + p2m + mi * 16 + fq * 4 + j));
      const bf16* ha = hin + (size_t)(p2m + fr) * H + ko;
      const bf16* wb = Whh + (size_t)(gc0 + fr) * H + ko;
      #pragma unroll 4
      for (int k = 0; k < 512; k += 32) {
        bf16x8s bv = ld8(wb + k);
        #pragma unroll
        for (int mi = 0; mi < 4; ++mi)
          acc[mi] = MFMA(ld8c(ha + mi * 16 * H + k), bv, acc[mi], 0, 0, 0);
      }
    }
    {
      const float* gb = t ? gbA : gb0;
      #pragma unroll
      for (int mi = 0; mi < 4; ++mi)
        #pragma unroll
        for (int j = 0; j < 4; ++j) {
          int rw = mi * 16 + fq * 4 + j;
          int grow = p2m + rw;
          int gcol = gc0 + fr;
          float v = acc[mi][j] + gb[gcol] +
              bf2f(*reinterpret_cast<const unsigned short*>(Gx + ((size_t)t * B + grow) * 2048 + gcol));
          smem[p2q * 2176 + rw * 34 + p2nh * 16 + fr] = v;
        }
    }
    __syncthreads();
    {
      int rw = tid >> 3, c0 = (tid & 7) << 2;
      int grow = p2m + rw;
      bool act = t < len[grow];
      union { unsigned short us[4]; u64 v; } hpk, hdk, hold;
      hold.v = aload(hin + (size_t)grow * H + p2j + c0);   // prev h (coherent)
      #pragma unroll
      for (int c = 0; c < 4; ++c) {
        int jl = c0 + c;
        float gi = sigm(smem[0 * 2176 + rw * 34 + jl]);
        float gf = sigm(smem[1 * 2176 + rw * 34 + jl]);
        float gg = tanhf(smem[2 * 2176 + rw * 34 + jl]);
        float go = sigm(smem[3 * 2176 + rw * 34 + jl]);
        int jg = p2j + jl;
        float cold = cst[(size_t)grow * H + jg];
        float c2 = gf * cold + gi * gg;
        float h2v = go * tanhf(c2);
        if (act) cst[(size_t)grow * H + jg] = c2;
        bf16 hb = __float2bfloat16(h2v);
        unsigned short hbits = *reinterpret_cast<const unsigned short*>(&hb);
        hpk.us[c] = act ? hbits : hold.us[c];
        hdk.us[c] = act ? hbits : (unsigned short)0;
      }
      astore(hout + (size_t)grow * H + p2j + c0, hpk.v);
      *reinterpret_cast<u64*>(hid + ((size_t)t * B + grow) * H + p2j + c0) = hdk.v;
    }
    __syncthreads();
  }
}

// ---------------- launch ----------------

extern "C" void kernel_launch(void* const* d_in, const int* in_sizes, int n_in,
                              void* d_out, int out_size, void* d_ws, size_t ws_size,
                              hipStream_t stream) {
  const float* feat   = (const float*)d_in[0];
  const int*   cap    = (const int*)d_in[1];
  const int*   len    = (const int*)d_in[2];
  const float* cnn    = (const float*)d_in[3];
  const float* embW   = (const float*)d_in[4];
  const float* Wih_f  = (const float*)d_in[5];
  const float* Whh_f  = (const float*)d_in[6];
  const float* bih    = (const float*)d_in[7];
  const float* bhh    = (const float*)d_in[8];
  const float* attW_f = (const float*)d_in[9];
  const float* attb   = (const float*)d_in[10];
  const float* attdW_f= (const float*)d_in[11];
  const float* attdb  = (const float*)d_in[12];
  const float* outW_f = (const float*)d_in[13];
  const float* outb   = (const float*)d_in[14];
  float* out = (float*)d_out;
  char* ws = (char*)d_ws;

  size_t off = 0;
  auto alloc = [&](size_t n) { char* p = ws + off; off += (n + 255) & ~(size_t)255; return p; };
  bf16*  xs    = (bf16*)alloc(8388608);
  bf16*  WaX   = (bf16*)alloc(524288);
  bf16*  WaH   = (bf16*)alloc(524288);
  bf16*  WdXT  = (bf16*)alloc(524288);
  bf16*  WdAT  = (bf16*)alloc(524288);
  bf16*  Wihb  = (bf16*)alloc(2097152);
  bf16*  Whhb  = (bf16*)alloc(2097152);
  bf16*  Kx    = (bf16*)alloc(2097152);
  bf16*  Kc    = (bf16*)alloc(2097152);
  bf16*  outWp = (bf16*)alloc(10354688);
  bf16*  Sxb   = (bf16*)alloc(8388608);
  bf16*  Gx    = (bf16*)alloc(33554432);
  bf16*  hid   = (bf16*)alloc(8388608);
  float* gb0   = (float*)alloc(8192);
  float* gbA   = (float*)alloc(8192);
  bf16*  h0    = (bf16*)alloc(131072);
  bf16*  h1    = (bf16*)alloc(131072);
  float* cst   = (float*)alloc(262144);
  bf16*  pbuf  = (bf16*)alloc(131072);
  float* Zbuf  = (float*)alloc(32768);
  int*   cnt   = (int*)alloc(256);

  kxs<<<4096, 256, 0, stream>>>(feat, cap, embW, xs);
  kslice<<<256, 256, 0, stream>>>(attW_f, WaX, 0);
  kslice<<<256, 256, 0, stream>>>(attW_f, WaH, 512);
  ktrans<<<256, 256, 0, stream>>>(attdW_f, WdXT, 0);
  ktrans<<<256, 256, 0, stream>>>(attdW_f, WdAT, 512);
  kcast<<<1024, 256, 0, stream>>>(Wih_f, Wihb, 262144);
  kcast<<<1024, 256, 0, stream>>>(Whh_f, Whhb, 262144);
  kpadW<<<5056, 256, 0, stream>>>(outW_f, outWp);
  kgb<<<8, 256, 0, stream>>>(bih, bhh, Wih_f, attdb, gb0, gbA);

  // precompute GEMMs (all K=512, A@B^T form)
  kgemm<1><<<256, 256, 0, stream>>>(xs, WaX, attb, nullptr, nullptr, Sxb, 4, 512);
  kgemm<1><<<64, 256, 0, stream>>>(Wihb, WdXT, nullptr, nullptr, nullptr, Kx, 4, 512);
  kgemm<1><<<64, 256, 0, stream>>>(Wihb, WdAT, nullptr, nullptr, nullptr, Kc, 4, 512);
  kgemm<1><<<1024, 256, 0, stream>>>(xs, Kx, nullptr, nullptr, nullptr, Gx, 16, 2048);
  kgemm<1><<<16, 256, 0, stream>>>(xs, Wihb, nullptr, nullptr, nullptr, Gx, 16, 2048); // t=0 rows

  hipMemsetAsync(cnt, 0, 256, stream);
  hipMemsetAsync(Zbuf, 0, 32768, stream);
  hipMemsetAsync(cst, 0, 262144, stream);
  hipMemsetAsync(h0, 0, 131072, stream);

  kloop<<<32, 512, 0, stream>>>(Sxb, Gx, Kc, Whhb, WaH, gb0, gbA, cnn, len,
                                h0, h1, cst, pbuf, Zbuf, hid, cnt);

  kgemm<0><<<5056, 256, 0, stream>>>(hid, outWp, outb, len, out, nullptr, 79, V);
}

// Round 4
// 3649.628 us; speedup vs baseline: 1.3681x; 1.3681x over previous
//
#include <hip/hip_runtime.h>
#include <hip/hip_bf16.h>

#define B 128
#define T 64
#define E 512
#define H 512
#define AA 512
#define V 10000

typedef __hip_bfloat16 bf16;
typedef unsigned long long u64;
typedef __attribute__((ext_vector_type(8))) short bf16x8s;
typedef __attribute__((ext_vector_type(4))) short s16x4;
typedef __attribute__((ext_vector_type(4))) float f32x4;

#define MFMA __builtin_amdgcn_mfma_f32_16x16x32_bf16

__device__ __forceinline__ bf16x8s ld8(const bf16* p) {
  return *reinterpret_cast<const bf16x8s*>(p);
}
__device__ __forceinline__ float sigm(float x) { return 1.f / (1.f + __expf(-x)); }
__device__ __forceinline__ float bf2f(unsigned short u) {
  return __uint_as_float(((unsigned)u) << 16);
}

// ---------------- grid barrier (32 same-XCD team blocks) ----------------
// Arrival/poll via agent-scope atomics (proven live in r3). Data moves via
// plain stores -> XCD L2 (L1 is write-through); __syncthreads drains vmcnt(0)
// before thread 0's arrive-add, so stores are L2-visible before arrival.
__device__ __forceinline__ void gbar(int* cnt, int target) {
  __syncthreads();
  if (threadIdx.x == 0) {
    __hip_atomic_fetch_add(cnt, 1, __ATOMIC_RELAXED, __HIP_MEMORY_SCOPE_AGENT);
    while (__hip_atomic_load(cnt, __ATOMIC_RELAXED, __HIP_MEMORY_SCOPE_AGENT) < target)
      __builtin_amdgcn_s_sleep(2);
  }
  __syncthreads();
}

// ---------------- prep kernels ----------------

__global__ __launch_bounds__(256) void kxs(const float* __restrict__ feat,
                                           const int* __restrict__ cap,
                                           const float* __restrict__ embW,
                                           bf16* __restrict__ xs) {
  int idx = blockIdx.x * 256 + threadIdx.x;   // B*T*E/4
  int e4 = (idx & 127) << 2;
  int b = (idx >> 7) & 127;
  int t = idx >> 14;
  const float* src = (t == 0) ? (feat + (size_t)b * E)
                              : (embW + (size_t)cap[b * (T - 1) + (t - 1)] * E);
  float4 v = *reinterpret_cast<const float4*>(src + e4);
  bf16* d = xs + ((size_t)t * B + b) * E + e4;
  d[0] = __float2bfloat16(v.x); d[1] = __float2bfloat16(v.y);
  d[2] = __float2bfloat16(v.z); d[3] = __float2bfloat16(v.w);
}

__global__ __launch_bounds__(256) void kcast(const float* __restrict__ s,
                                             bf16* __restrict__ d, int n4) {
  int i = blockIdx.x * 256 + threadIdx.x;
  if (i >= n4) return;
  float4 v = *reinterpret_cast<const float4*>(s + (size_t)i * 4);
  d[i * 4 + 0] = __float2bfloat16(v.x); d[i * 4 + 1] = __float2bfloat16(v.y);
  d[i * 4 + 2] = __float2bfloat16(v.z); d[i * 4 + 3] = __float2bfloat16(v.w);
}

// slice-cast: dst[r][0:512] = src[r][c0:c0+512], src ld=1024, R=512
__global__ __launch_bounds__(256) void kslice(const float* __restrict__ src,
                                              bf16* __restrict__ dst, int c0) {
  int i = blockIdx.x * 256 + threadIdx.x;   // 512*128
  int row = i >> 7, c4 = (i & 127) << 2;
  float4 v = *reinterpret_cast<const float4*>(src + (size_t)row * 1024 + c0 + c4);
  bf16* d = dst + (size_t)row * 512 + c4;
  d[0] = __float2bfloat16(v.x); d[1] = __float2bfloat16(v.y);
  d[2] = __float2bfloat16(v.z); d[3] = __float2bfloat16(v.w);
}

// transpose-cast: dst[a][e2] = src[e2][coff+a]; src (512 x ld1024)
__global__ __launch_bounds__(256) void ktrans(const float* __restrict__ src,
                                              bf16* __restrict__ dst, int coff) {
  __shared__ float tl[32][33];
  int bx = blockIdx.x & 15, by = blockIdx.x >> 4;
  int tx = threadIdx.x & 31, ty = threadIdx.x >> 5;
  for (int yy = ty; yy < 32; yy += 8)
    tl[yy][tx] = src[(size_t)(by * 32 + yy) * 1024 + coff + bx * 32 + tx];
  __syncthreads();
  for (int yy = ty; yy < 32; yy += 8)
    dst[(size_t)(bx * 32 + yy) * 512 + by * 32 + tx] = __float2bfloat16(tl[tx][yy]);
}

__global__ __launch_bounds__(256) void kpadW(const float* __restrict__ s,
                                             bf16* __restrict__ d) {
  int i = blockIdx.x * 256 + threadIdx.x;   // NPAD*H/4
  int row = (i << 2) / H;
  float4 v = make_float4(0.f, 0.f, 0.f, 0.f);
  if (row < V) v = *reinterpret_cast<const float4*>(s + (size_t)i * 4);
  d[i * 4 + 0] = __float2bfloat16(v.x); d[i * 4 + 1] = __float2bfloat16(v.y);
  d[i * 4 + 2] = __float2bfloat16(v.z); d[i * 4 + 3] = __float2bfloat16(v.w);
}

// gb0 = b_ih+b_hh ; gbA = gb0 + W_ih @ attd_b
__global__ __launch_bounds__(256) void kgb(const float* __restrict__ bih,
                                           const float* __restrict__ bhh,
                                           const float* __restrict__ Wih_f,
                                           const float* __restrict__ attdb,
                                           float* __restrict__ gb0,
                                           float* __restrict__ gbA) {
  int g = blockIdx.x * 256 + threadIdx.x;
  if (g >= 2048) return;
  float b0 = bih[g] + bhh[g];
  float s = 0.f;
  for (int e = 0; e < 512; ++e) s += Wih_f[(size_t)g * 512 + e] * attdb[e];
  gb0[g] = b0; gbA[g] = b0 + s;
}

// ---------------- m97-style GEMM: C[M,N] = A[M,512] @ Bw[N,512]^T ----------------
template<int EPI>
__global__ __launch_bounds__(256) void kgemm(const bf16* __restrict__ Ag,
                                             const bf16* __restrict__ Bg,
                                             const float* __restrict__ bias,
                                             const int* __restrict__ len,
                                             float* __restrict__ outF,
                                             bf16* __restrict__ outB,
                                             int nbn, int Nld) {
  __shared__ __align__(16) char lds[2][2][16384];   // [buf][A/B][128 rows x 64 bf16]
  const int nwg = gridDim.x;
  const int bid0 = blockIdx.x;
  const int wg = (bid0 & 7) * (nwg >> 3) + (bid0 >> 3);   // XCD swizzle (nwg % 8 == 0)
  const int bm = wg / nbn, bn = wg % nbn;
  const int tid = threadIdx.x, w = tid >> 6, lane = tid & 63;
  const int fr = lane & 15, fq = lane >> 4, ko = fq << 3;
  const int mh = w >> 1, nh = w & 1;
  const bf16* Abase = Ag + (size_t)bm * 128 * 512;
  const bf16* Bbase = Bg + (size_t)bn * 128 * 512;

  f32x4 acc[4][4] = {};

  auto STAGE = [&](int buf, int k0) {
    #pragma unroll
    for (int it = 0; it < 4; ++it) {
      int si = tid + it * 256;
      int row = si >> 3;
      int s = (si & 7) ^ (row & 7);
      __builtin_amdgcn_global_load_lds(
        (const __attribute__((address_space(1))) void*)(Abase + (size_t)row * 512 + k0 + s * 8),
        (__attribute__((address_space(3))) void*)(&lds[buf][0][((tid & ~63) + it * 256) * 16]),
        16, 0, 0);
    }
    #pragma unroll
    for (int it = 0; it < 4; ++it) {
      int si = tid + it * 256;
      int row = si >> 3;
      int s = (si & 7) ^ (row & 7);
      __builtin_amdgcn_global_load_lds(
        (const __attribute__((address_space(1))) void*)(Bbase + (size_t)row * 512 + k0 + s * 8),
        (__attribute__((address_space(3))) void*)(&lds[buf][1][((tid & ~63) + it * 256) * 16]),
        16, 0, 0);
    }
  };

  STAGE(0, 0);
  __syncthreads();
  for (int kt = 0; kt < 8; ++kt) {
    int cur = kt & 1;
    if (kt < 7) STAGE(cur ^ 1, (kt + 1) * 64);
    #pragma unroll
    for (int kk = 0; kk < 64; kk += 32) {
      bf16x8s a[4], b[4];
      #pragma unroll
      for (int i = 0; i < 4; ++i) {
        int ra = mh * 64 + i * 16 + fr;
        a[i] = *reinterpret_cast<const bf16x8s*>(
            &lds[cur][0][ra * 128 + ((((kk + ko) >> 3) ^ (ra & 7)) << 4)]);
        int rb = nh * 64 + i * 16 + fr;
        b[i] = *reinterpret_cast<const bf16x8s*>(
            &lds[cur][1][rb * 128 + ((((kk + ko) >> 3) ^ (rb & 7)) << 4)]);
      }
      #pragma unroll
      for (int mi = 0; mi < 4; ++mi)
        #pragma unroll
        for (int ni = 0; ni < 4; ++ni)
          acc[mi][ni] = MFMA(a[mi], b[ni], acc[mi][ni], 0, 0, 0);
    }
    __syncthreads();
  }

  #pragma unroll
  for (int mi = 0; mi < 4; ++mi)
    #pragma unroll
    for (int ni = 0; ni < 4; ++ni)
      #pragma unroll
      for (int j = 0; j < 4; ++j) {
        int row = bm * 128 + mh * 64 + mi * 16 + fq * 4 + j;
        int col = bn * 128 + nh * 64 + ni * 16 + fr;
        if (EPI == 0) {
          if (col < V) {
            int tt = row >> 7, bb = row & 127;
            outF[(size_t)row * V + col] = (tt < len[bb]) ? acc[mi][ni][j] + bias[col] : 0.f;
          }
        } else {
          float bv = bias ? bias[col] : 0.f;
          outB[(size_t)row * Nld + col] = __float2bfloat16(acc[mi][ni][j] + bv);
        }
      }
}

// ---------------- persistent sequential loop, XCD-local team ----------------
// 256 blocks launched; first XCD to collect 32 becomes the team; others exit.
// All cross-block data (h, P', Z) is T-indexed so consumers always read fresh
// addresses: L1-miss by construction -> shared XCD L2 (coherent, ~250 cyc).
__global__ __launch_bounds__(512, 1) void kloop(
    const bf16* __restrict__ Sxb,    // [T][B][512]
    const bf16* __restrict__ Gx,     // [T][B][2048]
    const bf16* __restrict__ Kc,     // [2048][512]
    const bf16* __restrict__ Whh,    // [2048][512]
    const bf16* __restrict__ WaH,    // [512][512]
    const float* __restrict__ gb0,
    const float* __restrict__ gbA,
    const float* __restrict__ cnn,   // [B][512] f32
    const int* __restrict__ len,
    bf16* __restrict__ hstore,       // [T][B][512]  (masked-with-prev h)
    float* __restrict__ cst,         // [B][512]
    bf16* __restrict__ pstore,       // [T][B][512]  (P' = exp*cnn)
    float* __restrict__ Zbuf,        // [T][B]
    bf16* __restrict__ hid,          // [T][B][512]  (masked-with-zero h)
    int* __restrict__ ticket,        // [16]
    int* __restrict__ winner,        // [1], init -1
    int* __restrict__ cnt) {
  __shared__ float smem[8704];       // p1: [8][32][33]  p2: [4][64][34]
  __shared__ int steam[2];

  // ---- election ----
  if (threadIdx.x == 0) {
    int xcc;
    asm volatile("s_getreg_b32 %0, hwreg(HW_REG_XCC_ID)" : "=s"(xcc));
    xcc &= 15;
    int my = __hip_atomic_fetch_add(&ticket[xcc], 1, __ATOMIC_RELAXED,
                                    __HIP_MEMORY_SCOPE_AGENT);
    if (my == 31) {
      int exp = -1;
      __hip_atomic_compare_exchange_strong(winner, &exp, xcc, __ATOMIC_RELAXED,
                                           __ATOMIC_RELAXED, __HIP_MEMORY_SCOPE_AGENT);
    }
    int wv;
    while ((wv = __hip_atomic_load(winner, __ATOMIC_RELAXED,
                                   __HIP_MEMORY_SCOPE_AGENT)) < 0)
      __builtin_amdgcn_s_sleep(8);
    steam[0] = (wv == xcc && my < 32) ? 1 : 0;
    steam[1] = my;
  }
  __syncthreads();
  if (!steam[0]) return;
  const int wid = steam[1];

  const int tid = threadIdx.x, w = tid >> 6, lane = tid & 63;
  const int fr = lane & 15, fq = lane >> 4, ko = fq << 3;
  // phase1: (m: 4x32 rows) x (n: 8x64 cols); wave = (ntile, kquarter)
  const int p1m = (wid & 3) << 5;
  const int p1n = (wid >> 2) << 6;
  const int p1nt = w & 1, p1kq = w >> 1;
  // phase2: (m: 2x64 rows) x (j: 16x32 h-cols); wave = (quarter, nhalf)
  const int p2m = (wid & 1) << 6;
  const int p2j = (wid >> 1) << 5;
  const int p2q = w >> 1, p2nh = w & 1;
  const int gc0 = p2q * 512 + p2j + p2nh * 16;

  int ep = 0;
  for (int t = 0; t < T; ++t) {
    const bf16* hin = hstore + (size_t)(t ? t - 1 : 0) * B * H;
    bf16* hout = hstore + (size_t)t * B * H;
    bf16* pt = pstore + (size_t)t * B * AA;
    if (t) {
      gbar(cnt, 32 * (++ep));        // h[t-1] ready (in L2)
      // ---- phase 1 ----
      {
        f32x4 acc[2][2] = {};
        const bf16* ha = hin + (size_t)(p1m + fr) * H + p1kq * 128 + ko;
        const bf16* wb = WaH + (size_t)(p1n + p1nt * 32 + fr) * H + p1kq * 128 + ko;
        #pragma unroll
        for (int k = 0; k < 128; k += 32) {
          bf16x8s a0 = ld8(ha + k), a1 = ld8(ha + 16 * H + k);
          bf16x8s b0 = ld8(wb + k), b1 = ld8(wb + 16 * H + k);
          acc[0][0] = MFMA(a0, b0, acc[0][0], 0, 0, 0);
          acc[0][1] = MFMA(a0, b1, acc[0][1], 0, 0, 0);
          acc[1][0] = MFMA(a1, b0, acc[1][0], 0, 0, 0);
          acc[1][1] = MFMA(a1, b1, acc[1][1], 0, 0, 0);
        }
        #pragma unroll
        for (int mi = 0; mi < 2; ++mi)
          #pragma unroll
          for (int ni = 0; ni < 2; ++ni)
            #pragma unroll
            for (int j = 0; j < 4; ++j)
              smem[w * 1056 + (mi * 16 + fq * 4 + j) * 33 + ni * 16 + fr] = acc[mi][ni][j];
      }
      __syncthreads();
      {
        int nt2 = tid >> 8, idx = tid & 255;
        int rw = idx >> 3, c0 = (idx & 7) << 2;
        int grow = p1m + rw;
        int gcol = p1n + nt2 * 32 + c0;
        s16x4 sx = *reinterpret_cast<const s16x4*>(Sxb + ((size_t)t * B + grow) * AA + gcol);
        float4 cv = *reinterpret_cast<const float4*>(cnn + (size_t)grow * AA + gcol);
        const float* cvp = reinterpret_cast<const float*>(&cv);
        float z = 0.f;
        union { s16x4 s; u64 v; } pv;
        #pragma unroll
        for (int c = 0; c < 4; ++c) {
          float s = 0.f;
          #pragma unroll
          for (int kq = 0; kq < 4; ++kq)
            s += smem[(kq * 2 + nt2) * 1056 + rw * 33 + c0 + c];
          float p = __expf(s + bf2f((unsigned short)sx[c]));
          z += p;
          bf16 pb = __float2bfloat16(p * cvp[c]);
          pv.s[c] = *reinterpret_cast<const short*>(&pb);
        }
        *reinterpret_cast<u64*>(pt + (size_t)grow * AA + gcol) = pv.v;
        z += __shfl_down(z, 4); z += __shfl_down(z, 2); z += __shfl_down(z, 1);
        if ((idx & 7) == 0)
          __hip_atomic_fetch_add(Zbuf + t * B + grow, z, __ATOMIC_RELAXED,
                                 __HIP_MEMORY_SCOPE_WORKGROUP);  // executes in XCD L2
      }
      gbar(cnt, 32 * (++ep));        // P'[t], Z[t] ready (in L2)
    }
    // ---- phase 2 ----
    f32x4 acc[4] = {};
    if (t) {
      const bf16* pa = pt + (size_t)(p2m + fr) * AA + ko;
      const bf16* kb = Kc + (size_t)(gc0 + fr) * AA + ko;
      #pragma unroll 4
      for (int k = 0; k < 512; k += 32) {
        bf16x8s bv = ld8(kb + k);
        #pragma unroll
        for (int mi = 0; mi < 4; ++mi)
          acc[mi] = MFMA(ld8(pa + mi * 16 * AA + k), bv, acc[mi], 0, 0, 0);
      }
      #pragma unroll
      for (int mi = 0; mi < 4; ++mi)
        #pragma unroll
        for (int j = 0; j < 4; ++j)
          acc[mi][j] *= __fdividef(1.f, Zbuf[t * B + p2m + mi * 16 + fq * 4 + j]);
      const bf16* ha = hin + (size_t)(p2m + fr) * H + ko;
      const bf16* wb = Whh + (size_t)(gc0 + fr) * H + ko;
      #pragma unroll 4
      for (int k = 0; k < 512; k += 32) {
        bf16x8s bv = ld8(wb + k);
        #pragma unroll
        for (int mi = 0; mi < 4; ++mi)
          acc[mi] = MFMA(ld8(ha + mi * 16 * H + k), bv, acc[mi], 0, 0, 0);
      }
    }
    {
      const float* gb = t ? gbA : gb0;
      #pragma unroll
      for (int mi = 0; mi < 4; ++mi)
        #pragma unroll
        for (int j = 0; j < 4; ++j) {
          int rw = mi * 16 + fq * 4 + j;
          int grow = p2m + rw;
          int gcol = gc0 + fr;
          float v = acc[mi][j] + gb[gcol] +
              bf2f(*reinterpret_cast<const unsigned short*>(Gx + ((size_t)t * B + grow) * 2048 + gcol));
          smem[p2q * 2176 + rw * 34 + p2nh * 16 + fr] = v;
        }
    }
    __syncthreads();
    {
      int rw = tid >> 3, c0 = (tid & 7) << 2;
      int grow = p2m + rw;
      bool act = t < len[grow];
      union { unsigned short us[4]; u64 v; } hpk, hdk, hold;
      hold.v = *reinterpret_cast<const u64*>(hin + (size_t)grow * H + p2j + c0);
      #pragma unroll
      for (int c = 0; c < 4; ++c) {
        int jl = c0 + c;
        float gi = sigm(smem[0 * 2176 + rw * 34 + jl]);
        float gf = sigm(smem[1 * 2176 + rw * 34 + jl]);
        float gg = tanhf(smem[2 * 2176 + rw * 34 + jl]);
        float go = sigm(smem[3 * 2176 + rw * 34 + jl]);
        int jg = p2j + jl;
        float cold = cst[(size_t)grow * H + jg];
        float c2 = gf * cold + gi * gg;
        float h2v = go * tanhf(c2);
        if (act) cst[(size_t)grow * H + jg] = c2;
        bf16 hb = __float2bfloat16(h2v);
        unsigned short hbits = *reinterpret_cast<const unsigned short*>(&hb);
        hpk.us[c] = act ? hbits : hold.us[c];
        hdk.us[c] = act ? hbits : (unsigned short)0;
      }
      *reinterpret_cast<u64*>(hout + (size_t)grow * H + p2j + c0) = hpk.v;
      *reinterpret_cast<u64*>(hid + ((size_t)t * B + grow) * H + p2j + c0) = hdk.v;
    }
    __syncthreads();
  }
}

// ---------------- launch ----------------

extern "C" void kernel_launch(void* const* d_in, const int* in_sizes, int n_in,
                              void* d_out, int out_size, void* d_ws, size_t ws_size,
                              hipStream_t stream) {
  const float* feat   = (const float*)d_in[0];
  const int*   cap    = (const int*)d_in[1];
  const int*   len    = (const int*)d_in[2];
  const float* cnn    = (const float*)d_in[3];
  const float* embW   = (const float*)d_in[4];
  const float* Wih_f  = (const float*)d_in[5];
  const float* Whh_f  = (const float*)d_in[6];
  const float* bih    = (const float*)d_in[7];
  const float* bhh    = (const float*)d_in[8];
  const float* attW_f = (const float*)d_in[9];
  const float* attb   = (const float*)d_in[10];
  const float* attdW_f= (const float*)d_in[11];
  const float* attdb  = (const float*)d_in[12];
  const float* outW_f = (const float*)d_in[13];
  const float* outb   = (const float*)d_in[14];
  float* out = (float*)d_out;
  char* ws = (char*)d_ws;

  size_t off = 0;
  auto alloc = [&](size_t n) { char* p = ws + off; off += (n + 255) & ~(size_t)255; return p; };
  bf16*  xs    = (bf16*)alloc(8388608);
  bf16*  WaX   = (bf16*)alloc(524288);
  bf16*  WaH   = (bf16*)alloc(524288);
  bf16*  WdXT  = (bf16*)alloc(524288);
  bf16*  WdAT  = (bf16*)alloc(524288);
  bf16*  Wihb  = (bf16*)alloc(2097152);
  bf16*  Whhb  = (bf16*)alloc(2097152);
  bf16*  Kc    = (bf16*)alloc(2097152);
  bf16*  outWp = (bf16*)alloc(10354688);
  bf16*  Sxb   = (bf16*)alloc(8388608);
  bf16*  Gx    = (bf16*)alloc(33554432);
  bf16*  hid   = (bf16*)alloc(8388608);
  bf16*  hstore= (bf16*)alloc(8388608);
  bf16*  pstore= (bf16*)alloc(8388608);
  float* gb0   = (float*)alloc(8192);
  float* gbA   = (float*)alloc(8192);
  float* cst   = (float*)alloc(262144);
  float* Zbuf  = (float*)alloc(32768);
  int*   ticket= (int*)alloc(256);
  int*   winner= (int*)alloc(256);
  int*   cnt   = (int*)alloc(256);
  bf16*  Kx    = pstore;   // Kx (2 MB) dead before kloop writes pstore

  kxs<<<4096, 256, 0, stream>>>(feat, cap, embW, xs);
  kslice<<<256, 256, 0, stream>>>(attW_f, WaX, 0);
  kslice<<<256, 256, 0, stream>>>(attW_f, WaH, 512);
  ktrans<<<256, 256, 0, stream>>>(attdW_f, WdXT, 0);
  ktrans<<<256, 256, 0, stream>>>(attdW_f, WdAT, 512);
  kcast<<<1024, 256, 0, stream>>>(Wih_f, Wihb, 262144);
  kcast<<<1024, 256, 0, stream>>>(Whh_f, Whhb, 262144);
  kpadW<<<5056, 256, 0, stream>>>(outW_f, outWp);
  kgb<<<8, 256, 0, stream>>>(bih, bhh, Wih_f, attdb, gb0, gbA);

  // precompute GEMMs (all K=512, A@B^T form)
  kgemm<1><<<256, 256, 0, stream>>>(xs, WaX, attb, nullptr, nullptr, Sxb, 4, 512);
  kgemm<1><<<64, 256, 0, stream>>>(Wihb, WdXT, nullptr, nullptr, nullptr, Kx, 4, 512);
  kgemm<1><<<64, 256, 0, stream>>>(Wihb, WdAT, nullptr, nullptr, nullptr, Kc, 4, 512);
  kgemm<1><<<1024, 256, 0, stream>>>(xs, Kx, nullptr, nullptr, nullptr, Gx, 16, 2048);
  kgemm<1><<<16, 256, 0, stream>>>(xs, Wihb, nullptr, nullptr, nullptr, Gx, 16, 2048); // t=0 rows

  hipMemsetAsync(ticket, 0, 256, stream);
  hipMemsetAsync(winner, 0xFF, 256, stream);   // -1
  hipMemsetAsync(cnt, 0, 256, stream);
  hipMemsetAsync(Zbuf, 0, 32768, stream);
  hipMemsetAsync(cst, 0, 262144, stream);

  kloop<<<256, 512, 0, stream>>>(Sxb, Gx, Kc, Whhb, WaH, gb0, gbA, cnn, len,
                                 hstore, cst, pstore, Zbuf, hid, ticket, winner, cnt);

  kgemm<0><<<5056, 256, 0, stream>>>(hid, outWp, outb, len, out, nullptr, 79, V);
}

// Round 5
// 2548.875 us; speedup vs baseline: 1.9589x; 1.4319x over previous
//
#include <hip/hip_runtime.h>
#include <hip/hip_bf16.h>

#define B 128
#define T 64
#define E 512
#define H 512
#define AA 512
#define V 10000

typedef __hip_bfloat16 bf16;
typedef unsigned long long u64;
typedef unsigned short u16;
typedef __attribute__((ext_vector_type(8))) short bf16x8s;
typedef __attribute__((ext_vector_type(4))) float f32x4;

#define MFMA __builtin_amdgcn_mfma_f32_16x16x32_bf16

__device__ __forceinline__ bf16x8s ld8(const bf16* p) {
  return *reinterpret_cast<const bf16x8s*>(p);
}
__device__ __forceinline__ float sigm(float x) { return 1.f / (1.f + __expf(-x)); }
__device__ __forceinline__ float bf2f(u16 u) {
  return __uint_as_float(((unsigned)u) << 16);
}

// ---------------- prep kernels ----------------

__global__ __launch_bounds__(256) void kxs(const float* __restrict__ feat,
                                           const int* __restrict__ cap,
                                           const float* __restrict__ embW,
                                           bf16* __restrict__ xs) {
  int idx = blockIdx.x * 256 + threadIdx.x;   // B*T*E/4
  int e4 = (idx & 127) << 2;
  int b = (idx >> 7) & 127;
  int t = idx >> 14;
  const float* src = (t == 0) ? (feat + (size_t)b * E)
                              : (embW + (size_t)cap[b * (T - 1) + (t - 1)] * E);
  float4 v = *reinterpret_cast<const float4*>(src + e4);
  bf16* d = xs + ((size_t)t * B + b) * E + e4;
  d[0] = __float2bfloat16(v.x); d[1] = __float2bfloat16(v.y);
  d[2] = __float2bfloat16(v.z); d[3] = __float2bfloat16(v.w);
}

__global__ __launch_bounds__(256) void kcast(const float* __restrict__ s,
                                             bf16* __restrict__ d, int n4) {
  int i = blockIdx.x * 256 + threadIdx.x;
  if (i >= n4) return;
  float4 v = *reinterpret_cast<const float4*>(s + (size_t)i * 4);
  d[i * 4 + 0] = __float2bfloat16(v.x); d[i * 4 + 1] = __float2bfloat16(v.y);
  d[i * 4 + 2] = __float2bfloat16(v.z); d[i * 4 + 3] = __float2bfloat16(v.w);
}

__global__ __launch_bounds__(256) void kslice(const float* __restrict__ src,
                                              bf16* __restrict__ dst, int c0) {
  int i = blockIdx.x * 256 + threadIdx.x;   // 512*128
  int row = i >> 7, c4 = (i & 127) << 2;
  float4 v = *reinterpret_cast<const float4*>(src + (size_t)row * 1024 + c0 + c4);
  bf16* d = dst + (size_t)row * 512 + c4;
  d[0] = __float2bfloat16(v.x); d[1] = __float2bfloat16(v.y);
  d[2] = __float2bfloat16(v.z); d[3] = __float2bfloat16(v.w);
}

__global__ __launch_bounds__(256) void ktrans(const float* __restrict__ src,
                                              bf16* __restrict__ dst, int coff) {
  __shared__ float tl[32][33];
  int bx = blockIdx.x & 15, by = blockIdx.x >> 4;
  int tx = threadIdx.x & 31, ty = threadIdx.x >> 5;
  for (int yy = ty; yy < 32; yy += 8)
    tl[yy][tx] = src[(size_t)(by * 32 + yy) * 1024 + coff + bx * 32 + tx];
  __syncthreads();
  for (int yy = ty; yy < 32; yy += 8)
    dst[(size_t)(bx * 32 + yy) * 512 + by * 32 + tx] = __float2bfloat16(tl[tx][yy]);
}

__global__ __launch_bounds__(256) void kpadW(const float* __restrict__ s,
                                             bf16* __restrict__ d) {
  int i = blockIdx.x * 256 + threadIdx.x;   // NPAD*H/4
  int row = (i << 2) / H;
  float4 v = make_float4(0.f, 0.f, 0.f, 0.f);
  if (row < V) v = *reinterpret_cast<const float4*>(s + (size_t)i * 4);
  d[i * 4 + 0] = __float2bfloat16(v.x); d[i * 4 + 1] = __float2bfloat16(v.y);
  d[i * 4 + 2] = __float2bfloat16(v.z); d[i * 4 + 3] = __float2bfloat16(v.w);
}

__global__ __launch_bounds__(256) void kgb(const float* __restrict__ bih,
                                           const float* __restrict__ bhh,
                                           const float* __restrict__ Wih_f,
                                           const float* __restrict__ attdb,
                                           float* __restrict__ gb0,
                                           float* __restrict__ gbA) {
  int g = blockIdx.x * 256 + threadIdx.x;
  if (g >= 2048) return;
  float b0 = bih[g] + bhh[g];
  float s = 0.f;
  for (int e = 0; e < 512; ++e) s += Wih_f[(size_t)g * 512 + e] * attdb[e];
  gb0[g] = b0; gbA[g] = b0 + s;
}

// ---------------- m97-style GEMM (bf16 out) for precompute ----------------
__global__ __launch_bounds__(256) void kgemm(const bf16* __restrict__ Ag,
                                             const bf16* __restrict__ Bg,
                                             const float* __restrict__ bias,
                                             bf16* __restrict__ outB,
                                             int nbn, int Nld) {
  __shared__ __align__(16) char lds[2][2][16384];
  const int nwg = gridDim.x;
  const int bid0 = blockIdx.x;
  const int wg = (bid0 & 7) * (nwg >> 3) + (bid0 >> 3);
  const int bm = wg / nbn, bn = wg % nbn;
  const int tid = threadIdx.x, w = tid >> 6, lane = tid & 63;
  const int fr = lane & 15, fq = lane >> 4, ko = fq << 3;
  const int mh = w >> 1, nh = w & 1;
  const bf16* Abase = Ag + (size_t)bm * 128 * 512;
  const bf16* Bbase = Bg + (size_t)bn * 128 * 512;
  f32x4 acc[4][4] = {};
  auto STAGE = [&](int buf, int k0) {
    #pragma unroll
    for (int m = 0; m < 2; ++m) {
      const bf16* base = m ? Bbase : Abase;
      #pragma unroll
      for (int it = 0; it < 4; ++it) {
        int si = tid + it * 256;
        int row = si >> 3;
        int s = (si & 7) ^ (row & 7);
        __builtin_amdgcn_global_load_lds(
          (const __attribute__((address_space(1))) void*)(base + (size_t)row * 512 + k0 + s * 8),
          (__attribute__((address_space(3))) void*)(&lds[buf][m][((tid & ~63) + it * 256) * 16]),
          16, 0, 0);
      }
    }
  };
  STAGE(0, 0);
  __syncthreads();
  for (int kt = 0; kt < 8; ++kt) {
    int cur = kt & 1;
    if (kt < 7) STAGE(cur ^ 1, (kt + 1) * 64);
    #pragma unroll
    for (int kk = 0; kk < 64; kk += 32) {
      bf16x8s a[4], b[4];
      #pragma unroll
      for (int i = 0; i < 4; ++i) {
        int ra = mh * 64 + i * 16 + fr;
        a[i] = *reinterpret_cast<const bf16x8s*>(
            &lds[cur][0][ra * 128 + ((((kk + ko) >> 3) ^ (ra & 7)) << 4)]);
        int rb = nh * 64 + i * 16 + fr;
        b[i] = *reinterpret_cast<const bf16x8s*>(
            &lds[cur][1][rb * 128 + ((((kk + ko) >> 3) ^ (rb & 7)) << 4)]);
      }
      #pragma unroll
      for (int mi = 0; mi < 4; ++mi)
        #pragma unroll
        for (int ni = 0; ni < 4; ++ni)
          acc[mi][ni] = MFMA(a[mi], b[ni], acc[mi][ni], 0, 0, 0);
    }
    __syncthreads();
  }
  #pragma unroll
  for (int mi = 0; mi < 4; ++mi)
    #pragma unroll
    for (int ni = 0; ni < 4; ++ni)
      #pragma unroll
      for (int j = 0; j < 4; ++j) {
        int row = bm * 128 + mh * 64 + mi * 16 + fq * 4 + j;
        int col = bn * 128 + nh * 64 + ni * 16 + fr;
        float bv = bias ? bias[col] : 0.f;
        outB[(size_t)row * Nld + col] = __float2bfloat16(acc[mi][ni][j] + bv);
      }
}

// ---------------- kfinal: 128x128 tile, K-step 32, 32KB LDS, 4 blocks/CU ----------------
__global__ __launch_bounds__(256, 4) void kfinal(const bf16* __restrict__ Ag,
                                                 const bf16* __restrict__ Bg,
                                                 const float* __restrict__ bias,
                                                 const int* __restrict__ len,
                                                 float* __restrict__ out) {
  __shared__ __align__(16) char lds[2][2][8192];   // [buf][A/B][128 rows x 32 bf16]
  const int nwg = gridDim.x;                       // 5056
  const int bid0 = blockIdx.x;
  const int wg = (bid0 & 7) * (nwg >> 3) + (bid0 >> 3);
  const int bm = wg / 79, bn = wg % 79;
  const int tid = threadIdx.x, w = tid >> 6, lane = tid & 63;
  const int fr = lane & 15, fq = lane >> 4;
  const int mh = w >> 1, nh = w & 1;
  const bf16* Abase = Ag + (size_t)bm * 128 * 512;
  const bf16* Bbase = Bg + (size_t)bn * 128 * 512;
  f32x4 acc[4][4] = {};
  auto STAGE = [&](int buf, int k0) {
    #pragma unroll
    for (int m = 0; m < 2; ++m) {
      const bf16* base = m ? Bbase : Abase;
      #pragma unroll
      for (int it = 0; it < 2; ++it) {
        int u = it * 256 + tid;
        int row = u >> 2, c = u & 3;
        int cs = c ^ ((row >> 1) & 3);
        __builtin_amdgcn_global_load_lds(
          (const __attribute__((address_space(1))) void*)(base + (size_t)row * 512 + k0 + cs * 8),
          (__attribute__((address_space(3))) void*)(&lds[buf][m][((tid & ~63) + it * 256) * 16]),
          16, 0, 0);
      }
    }
  };
  STAGE(0, 0);
  __syncthreads();
  for (int kt = 0; kt < 16; ++kt) {
    int cur = kt & 1;
    if (kt < 15) STAGE(cur ^ 1, (kt + 1) * 32);
    bf16x8s a[4], b[4];
    #pragma unroll
    for (int i = 0; i < 4; ++i) {
      int ra = mh * 64 + i * 16 + fr;
      a[i] = *reinterpret_cast<const bf16x8s*>(
          &lds[cur][0][ra * 64 + ((fq ^ ((ra >> 1) & 3)) << 4)]);
      int rb = nh * 64 + i * 16 + fr;
      b[i] = *reinterpret_cast<const bf16x8s*>(
          &lds[cur][1][rb * 64 + ((fq ^ ((rb >> 1) & 3)) << 4)]);
    }
    #pragma unroll
    for (int mi = 0; mi < 4; ++mi)
      #pragma unroll
      for (int ni = 0; ni < 4; ++ni)
        acc[mi][ni] = MFMA(a[mi], b[ni], acc[mi][ni], 0, 0, 0);
    __syncthreads();
  }
  #pragma unroll
  for (int mi = 0; mi < 4; ++mi)
    #pragma unroll
    for (int ni = 0; ni < 4; ++ni)
      #pragma unroll
      for (int j = 0; j < 4; ++j) {
        int row = bm * 128 + mh * 64 + mi * 16 + fq * 4 + j;
        int col = bn * 128 + nh * 64 + ni * 16 + fr;
        if (col < V) {
          int tt = row >> 7, bb = row & 127;
          out[(size_t)row * V + col] = (tt < len[bb]) ? acc[mi][ni][j] + bias[col] : 0.f;
        }
      }
}

// ---------------- persistent sequential loop, XCD-local, LDS-pinned Kc ----------------
// 256 blocks launched; first XCD to collect 32 becomes the team; others exit.
// Cross-block data (h, P', Z) T-indexed -> fresh addresses -> shared XCD L2.
// Kc in LDS (64KB); Whh/WaH L2-resident; Gx/Sx nontemporal streamed; c/h in regs.
__global__ __launch_bounds__(512, 1) void kloop(
    const bf16* __restrict__ Sxb,    // [T][B][512]
    const bf16* __restrict__ Gx,     // [T][B][2048]
    const bf16* __restrict__ Kc,     // [2048][512]
    const bf16* __restrict__ Whh,    // [2048][512]
    const bf16* __restrict__ WaH,    // [512][512]
    const float* __restrict__ gb0,
    const float* __restrict__ gbA,
    const float* __restrict__ cnn,   // [B][512] f32
    const int* __restrict__ len,
    bf16* __restrict__ hstore,       // [T][B][512]
    bf16* __restrict__ pstore,       // [T][B][512]
    float* __restrict__ Zbuf,        // [T][B]
    bf16* __restrict__ hid,          // [T][B][512]
    int* ticket, int* winner, int* cnt) {
  __shared__ __align__(16) char KcS[65536];   // [4 quarters][16 rows][512] swizzled
  __shared__ int steam[2];

  if (threadIdx.x == 0) {
    int xcc;
    asm volatile("s_getreg_b32 %0, hwreg(HW_REG_XCC_ID)" : "=s"(xcc));
    xcc &= 15;
    int my = __hip_atomic_fetch_add(&ticket[xcc], 1, __ATOMIC_RELAXED,
                                    __HIP_MEMORY_SCOPE_AGENT);
    if (my == 31) {
      int exp = -1;
      __hip_atomic_compare_exchange_strong(winner, &exp, xcc, __ATOMIC_RELAXED,
                                           __ATOMIC_RELAXED, __HIP_MEMORY_SCOPE_AGENT);
    }
    int wv;
    while ((wv = __hip_atomic_load(winner, __ATOMIC_RELAXED,
                                   __HIP_MEMORY_SCOPE_AGENT)) < 0)
      __builtin_amdgcn_s_sleep(8);
    steam[0] = (wv == xcc && my < 32) ? 1 : 0;
    steam[1] = my;
  }
  __syncthreads();
  if (!steam[0]) return;
  const int wid = steam[1];

  const int tid = threadIdx.x, w = tid >> 6, lane = tid & 63;
  const int fr = lane & 15, fq = lane >> 4, ko = fq << 3;
  const int cb = wid << 4;              // this block's 16-col slice (att & hidden)
  const int col = cb + fr;

  // preload Kc slice into LDS, chunk-XOR swizzled (row = q*16 + r)
  for (int u = tid; u < 4096; u += 512) {
    int row = u >> 6, chunk = u & 63;
    int g = (row >> 4) * 512 + cb + (row & 15);
    bf16x8s v = ld8(Kc + (size_t)g * 512 + chunk * 8);
    *reinterpret_cast<bf16x8s*>(&KcS[row * 1024 + ((chunk ^ (row & 7)) << 4)]) = v;
  }

  const int r0 = w * 16 + fq * 4;       // this thread's 4 rows: r0..r0+3
  int4 lv4 = *reinterpret_cast<const int4*>(len + r0);
  int lv[4] = {lv4.x, lv4.y, lv4.z, lv4.w};
  float cnnv[4], gb0v[4], gbAv[4];
  #pragma unroll
  for (int j = 0; j < 4; ++j) cnnv[j] = cnn[(size_t)(r0 + j) * AA + col];
  #pragma unroll
  for (int q = 0; q < 4; ++q) {
    gb0v[q] = gb0[q * 512 + col];
    gbAv[q] = gbA[q * 512 + col];
  }
  float cstv[4] = {0.f, 0.f, 0.f, 0.f};
  u16 hpv[4] = {0, 0, 0, 0};
  __syncthreads();   // KcS ready

  int ep = 0;
  for (int t = 0; t < T; ++t) {
    // ---- arrive A (publish h[t-1]) ----
    if (t) {
      __syncthreads();
      if (tid == 0)
        __hip_atomic_fetch_add(cnt, 1, __ATOMIC_RELAXED, __HIP_MEMORY_SCOPE_AGENT);
      ++ep;
    }
    // ---- prefetch streams (independent of recurrence) ----
    u16 gxv[16];
    u16 sxv[4] = {0, 0, 0, 0};
    #pragma unroll
    for (int q = 0; q < 4; ++q)
      #pragma unroll
      for (int j = 0; j < 4; ++j)
        gxv[q * 4 + j] = __builtin_nontemporal_load(
            (const u16*)Gx + ((size_t)t * B + r0 + j) * 2048 + q * 512 + col);
    if (t) {
      #pragma unroll
      for (int j = 0; j < 4; ++j)
        sxv[j] = __builtin_nontemporal_load(
            (const u16*)Sxb + ((size_t)t * B + r0 + j) * AA + col);
    }
    const bf16* hin = hstore + (size_t)(t ? t - 1 : 0) * B * H;
    bf16* pst = pstore + (size_t)t * B * AA;
    // ---- wait A + phase 1 ----
    if (t) {
      if (tid == 0)
        while (__hip_atomic_load(cnt, __ATOMIC_RELAXED, __HIP_MEMORY_SCOPE_AGENT) < 32 * ep)
          __builtin_amdgcn_s_sleep(1);
      __syncthreads();
      f32x4 acc1 = {};
      {
        const bf16* ha = hin + (size_t)(w * 16 + fr) * H + ko;
        const bf16* wb = WaH + (size_t)col * H + ko;
        #pragma unroll 4
        for (int k = 0; k < 512; k += 32)
          acc1 = MFMA(ld8(ha + k), ld8(wb + k), acc1, 0, 0, 0);
      }
      float pj[4];
      #pragma unroll
      for (int j = 0; j < 4; ++j) {
        pj[j] = __expf(acc1[j] + bf2f(sxv[j]));
        bf16 pb = __float2bfloat16(pj[j] * cnnv[j]);
        pst[(size_t)(r0 + j) * AA + col] = pb;
      }
      #pragma unroll
      for (int j = 0; j < 4; ++j) {
        float z = pj[j];
        z += __shfl_xor(z, 1); z += __shfl_xor(z, 2);
        z += __shfl_xor(z, 4); z += __shfl_xor(z, 8);
        if (fr == 0)
          __hip_atomic_fetch_add(Zbuf + t * B + r0 + j, z, __ATOMIC_RELAXED,
                                 __HIP_MEMORY_SCOPE_WORKGROUP);  // lands in XCD L2
      }
      // ---- arrive B (publish P', Z) ----
      __syncthreads();
      if (tid == 0)
        __hip_atomic_fetch_add(cnt, 1, __ATOMIC_RELAXED, __HIP_MEMORY_SCOPE_AGENT);
      ++ep;
    }
    // ---- H-GEMM (overlaps barrier-B propagation) + wait B + P-GEMM ----
    f32x4 accH[4] = {}, accP[4] = {};
    if (t) {
      {
        const bf16* ha = hin + (size_t)(w * 16 + fr) * H + ko;
        #pragma unroll 2
        for (int k = 0; k < 512; k += 32) {
          bf16x8s a = ld8(ha + k);
          #pragma unroll
          for (int q = 0; q < 4; ++q)
            accH[q] = MFMA(a, ld8(Whh + (size_t)(q * 512 + col) * H + ko + k),
                           accH[q], 0, 0, 0);
        }
      }
      if (tid == 0)
        while (__hip_atomic_load(cnt, __ATOMIC_RELAXED, __HIP_MEMORY_SCOPE_AGENT) < 32 * ep)
          __builtin_amdgcn_s_sleep(1);
      __syncthreads();
      {
        const bf16* pa = pst + (size_t)(w * 16 + fr) * AA + ko;
        #pragma unroll 2
        for (int k = 0; k < 512; k += 32) {
          bf16x8s a = ld8(pa + k);
          #pragma unroll
          for (int q = 0; q < 4; ++q) {
            bf16x8s b = *reinterpret_cast<const bf16x8s*>(
                &KcS[(q * 16 + fr) * 1024 + ((((k >> 3) + fq) ^ (fr & 7)) << 4)]);
            accP[q] = MFMA(a, b, accP[q], 0, 0, 0);
          }
        }
      }
      float4 zv = *reinterpret_cast<const float4*>(Zbuf + t * B + r0);
      float zp[4] = {zv.x, zv.y, zv.z, zv.w};
      #pragma unroll
      for (int q = 0; q < 4; ++q)
        #pragma unroll
        for (int j = 0; j < 4; ++j)
          accP[q][j] *= __fdividef(1.f, zp[j]);
    }
    // ---- gates + cell (all in registers) ----
    float gsel[4];
    #pragma unroll
    for (int q = 0; q < 4; ++q) gsel[q] = t ? gbAv[q] : gb0v[q];
    #pragma unroll
    for (int j = 0; j < 4; ++j) {
      float gi = sigm(accP[0][j] + accH[0][j] + gsel[0] + bf2f(gxv[0 + j]));
      float gf = sigm(accP[1][j] + accH[1][j] + gsel[1] + bf2f(gxv[4 + j]));
      float gg = tanhf(accP[2][j] + accH[2][j] + gsel[2] + bf2f(gxv[8 + j]));
      float go = sigm(accP[3][j] + accH[3][j] + gsel[3] + bf2f(gxv[12 + j]));
      float c2 = gf * cstv[j] + gi * gg;
      float h2 = go * tanhf(c2);
      bool act = t < lv[j];
      if (act) cstv[j] = c2;
      bf16 hb = __float2bfloat16(h2);
      u16 hbits = *reinterpret_cast<u16*>(&hb);
      hpv[j] = act ? hbits : hpv[j];
      ((u16*)hstore)[((size_t)t * B + r0 + j) * H + col] = hpv[j];
      __builtin_nontemporal_store(act ? hbits : (u16)0,
          (u16*)hid + ((size_t)t * B + r0 + j) * H + col);
    }
  }
}

// ---------------- launch ----------------

extern "C" void kernel_launch(void* const* d_in, const int* in_sizes, int n_in,
                              void* d_out, int out_size, void* d_ws, size_t ws_size,
                              hipStream_t stream) {
  const float* feat   = (const float*)d_in[0];
  const int*   cap    = (const int*)d_in[1];
  const int*   len    = (const int*)d_in[2];
  const float* cnn    = (const float*)d_in[3];
  const float* embW   = (const float*)d_in[4];
  const float* Wih_f  = (const float*)d_in[5];
  const float* Whh_f  = (const float*)d_in[6];
  const float* bih    = (const float*)d_in[7];
  const float* bhh    = (const float*)d_in[8];
  const float* attW_f = (const float*)d_in[9];
  const float* attb   = (const float*)d_in[10];
  const float* attdW_f= (const float*)d_in[11];
  const float* attdb  = (const float*)d_in[12];
  const float* outW_f = (const float*)d_in[13];
  const float* outb   = (const float*)d_in[14];
  float* out = (float*)d_out;
  char* ws = (char*)d_ws;

  size_t off = 0;
  auto alloc = [&](size_t n) { char* p = ws + off; off += (n + 255) & ~(size_t)255; return p; };
  bf16*  xs    = (bf16*)alloc(8388608);
  bf16*  WaX   = (bf16*)alloc(524288);
  bf16*  WaH   = (bf16*)alloc(524288);
  bf16*  WdXT  = (bf16*)alloc(524288);
  bf16*  WdAT  = (bf16*)alloc(524288);
  bf16*  Wihb  = (bf16*)alloc(2097152);
  bf16*  Whhb  = (bf16*)alloc(2097152);
  bf16*  Kc    = (bf16*)alloc(2097152);
  bf16*  outWp = (bf16*)alloc(10354688);
  bf16*  Sxb   = (bf16*)alloc(8388608);
  bf16*  Gx    = (bf16*)alloc(33554432);
  bf16*  hid   = (bf16*)alloc(8388608);
  bf16*  hstore= (bf16*)alloc(8388608);
  bf16*  pstore= (bf16*)alloc(8388608);
  float* gb0   = (float*)alloc(8192);
  float* gbA   = (float*)alloc(8192);
  float* Zbuf  = (float*)alloc(32768);
  int*   ticket= (int*)alloc(256);
  int*   winner= (int*)alloc(256);
  int*   cnt   = (int*)alloc(256);
  bf16*  Kx    = pstore;   // Kx (2 MB) dead before kloop writes pstore

  kxs<<<4096, 256, 0, stream>>>(feat, cap, embW, xs);
  kslice<<<256, 256, 0, stream>>>(attW_f, WaX, 0);
  kslice<<<256, 256, 0, stream>>>(attW_f, WaH, 512);
  ktrans<<<256, 256, 0, stream>>>(attdW_f, WdXT, 0);
  ktrans<<<256, 256, 0, stream>>>(attdW_f, WdAT, 512);
  kcast<<<1024, 256, 0, stream>>>(Wih_f, Wihb, 262144);
  kcast<<<1024, 256, 0, stream>>>(Whh_f, Whhb, 262144);
  kpadW<<<5056, 256, 0, stream>>>(outW_f, outWp);
  kgb<<<8, 256, 0, stream>>>(bih, bhh, Wih_f, attdb, gb0, gbA);

  // precompute GEMMs (all K=512, A@B^T form)
  kgemm<<<256, 256, 0, stream>>>(xs, WaX, attb, Sxb, 4, 512);
  kgemm<<<64, 256, 0, stream>>>(Wihb, WdXT, nullptr, Kx, 4, 512);
  kgemm<<<64, 256, 0, stream>>>(Wihb, WdAT, nullptr, Kc, 4, 512);
  kgemm<<<1024, 256, 0, stream>>>(xs, Kx, nullptr, Gx, 16, 2048);
  kgemm<<<16, 256, 0, stream>>>(xs, Wihb, nullptr, Gx, 16, 2048); // t=0 rows

  hipMemsetAsync(ticket, 0, 256, stream);
  hipMemsetAsync(winner, 0xFF, 256, stream);   // -1
  hipMemsetAsync(cnt, 0, 256, stream);
  hipMemsetAsync(Zbuf, 0, 32768, stream);

  kloop<<<256, 512, 0, stream>>>(Sxb, Gx, Kc, Whhb, WaH, gb0, gbA, cnn, len,
                                 hstore, pstore, Zbuf, hid, ticket, winner, cnt);

  kfinal<<<5056, 256, 0, stream>>>(hid, outWp, outb, len, out);
}

// Round 7
// 1705.680 us; speedup vs baseline: 2.9273x; 1.4943x over previous
//
#include <hip/hip_runtime.h>
#include <hip/hip_bf16.h>

#define B 128
#define T 64
#define E 512
#define H 512
#define AA 512
#define V 10000

typedef __hip_bfloat16 bf16;
typedef unsigned long long u64;
typedef unsigned short u16;
typedef __attribute__((ext_vector_type(8))) short bf16x8s;
typedef __attribute__((ext_vector_type(4))) float f32x4;

#define MFMA __builtin_amdgcn_mfma_f32_16x16x32_bf16

__device__ __forceinline__ bf16x8s ld8(const bf16* p) {
  return *reinterpret_cast<const bf16x8s*>(p);
}
__device__ __forceinline__ float sigm(float x) { return 1.f / (1.f + __expf(-x)); }
__device__ __forceinline__ float bf2f(u16 u) {
  return __uint_as_float(((unsigned)u) << 16);
}

// ---------------- prep kernels ----------------

__global__ __launch_bounds__(256) void kxs(const float* __restrict__ feat,
                                           const int* __restrict__ cap,
                                           const float* __restrict__ embW,
                                           bf16* __restrict__ xs) {
  int idx = blockIdx.x * 256 + threadIdx.x;   // B*T*E/4
  int e4 = (idx & 127) << 2;
  int b = (idx >> 7) & 127;
  int t = idx >> 14;
  const float* src = (t == 0) ? (feat + (size_t)b * E)
                              : (embW + (size_t)cap[b * (T - 1) + (t - 1)] * E);
  float4 v = *reinterpret_cast<const float4*>(src + e4);
  bf16* d = xs + ((size_t)t * B + b) * E + e4;
  d[0] = __float2bfloat16(v.x); d[1] = __float2bfloat16(v.y);
  d[2] = __float2bfloat16(v.z); d[3] = __float2bfloat16(v.w);
}

__global__ __launch_bounds__(256) void kcast(const float* __restrict__ s,
                                             bf16* __restrict__ d, int n4) {
  int i = blockIdx.x * 256 + threadIdx.x;
  if (i >= n4) return;
  float4 v = *reinterpret_cast<const float4*>(s + (size_t)i * 4);
  d[i * 4 + 0] = __float2bfloat16(v.x); d[i * 4 + 1] = __float2bfloat16(v.y);
  d[i * 4 + 2] = __float2bfloat16(v.z); d[i * 4 + 3] = __float2bfloat16(v.w);
}

__global__ __launch_bounds__(256) void kslice(const float* __restrict__ src,
                                              bf16* __restrict__ dst, int c0) {
  int i = blockIdx.x * 256 + threadIdx.x;   // 512*128
  int row = i >> 7, c4 = (i & 127) << 2;
  float4 v = *reinterpret_cast<const float4*>(src + (size_t)row * 1024 + c0 + c4);
  bf16* d = dst + (size_t)row * 512 + c4;
  d[0] = __float2bfloat16(v.x); d[1] = __float2bfloat16(v.y);
  d[2] = __float2bfloat16(v.z); d[3] = __float2bfloat16(v.w);
}

__global__ __launch_bounds__(256) void ktrans(const float* __restrict__ src,
                                              bf16* __restrict__ dst, int coff) {
  __shared__ float tl[32][33];
  int bx = blockIdx.x & 15, by = blockIdx.x >> 4;
  int tx = threadIdx.x & 31, ty = threadIdx.x >> 5;
  for (int yy = ty; yy < 32; yy += 8)
    tl[yy][tx] = src[(size_t)(by * 32 + yy) * 1024 + coff + bx * 32 + tx];
  __syncthreads();
  for (int yy = ty; yy < 32; yy += 8)
    dst[(size_t)(bx * 32 + yy) * 512 + by * 32 + tx] = __float2bfloat16(tl[tx][yy]);
}

__global__ __launch_bounds__(256) void kpadW(const float* __restrict__ s,
                                             bf16* __restrict__ d) {
  int i = blockIdx.x * 256 + threadIdx.x;   // NPAD*H/4
  int row = (i << 2) / H;
  float4 v = make_float4(0.f, 0.f, 0.f, 0.f);
  if (row < V) v = *reinterpret_cast<const float4*>(s + (size_t)i * 4);
  d[i * 4 + 0] = __float2bfloat16(v.x); d[i * 4 + 1] = __float2bfloat16(v.y);
  d[i * 4 + 2] = __float2bfloat16(v.z); d[i * 4 + 3] = __float2bfloat16(v.w);
}

__global__ __launch_bounds__(256) void kgb(const float* __restrict__ bih,
                                           const float* __restrict__ bhh,
                                           const float* __restrict__ Wih_f,
                                           const float* __restrict__ attdb,
                                           float* __restrict__ gb0,
                                           float* __restrict__ gbA) {
  int g = blockIdx.x * 256 + threadIdx.x;
  if (g >= 2048) return;
  float b0 = bih[g] + bhh[g];
  float s = 0.f;
  for (int e = 0; e < 512; ++e) s += Wih_f[(size_t)g * 512 + e] * attdb[e];
  gb0[g] = b0; gbA[g] = b0 + s;
}

// ---------------- m97-style GEMM (bf16 out) for precompute ----------------
__global__ __launch_bounds__(256) void kgemm(const bf16* __restrict__ Ag,
                                             const bf16* __restrict__ Bg,
                                             const float* __restrict__ bias,
                                             bf16* __restrict__ outB,
                                             int nbn, int Nld) {
  __shared__ __align__(16) char lds[2][2][16384];
  const int nwg = gridDim.x;
  const int bid0 = blockIdx.x;
  const int wg = (bid0 & 7) * (nwg >> 3) + (bid0 >> 3);
  const int bm = wg / nbn, bn = wg % nbn;
  const int tid = threadIdx.x, w = tid >> 6, lane = tid & 63;
  const int fr = lane & 15, fq = lane >> 4, ko = fq << 3;
  const int mh = w >> 1, nh = w & 1;
  const bf16* Abase = Ag + (size_t)bm * 128 * 512;
  const bf16* Bbase = Bg + (size_t)bn * 128 * 512;
  f32x4 acc[4][4] = {};
  auto STAGE = [&](int buf, int k0) {
    #pragma unroll
    for (int m = 0; m < 2; ++m) {
      const bf16* base = m ? Bbase : Abase;
      #pragma unroll
      for (int it = 0; it < 4; ++it) {
        int si = tid + it * 256;
        int row = si >> 3;
        int s = (si & 7) ^ (row & 7);
        __builtin_amdgcn_global_load_lds(
          (const __attribute__((address_space(1))) void*)(base + (size_t)row * 512 + k0 + s * 8),
          (__attribute__((address_space(3))) void*)(&lds[buf][m][((tid & ~63) + it * 256) * 16]),
          16, 0, 0);
      }
    }
  };
  STAGE(0, 0);
  __syncthreads();
  for (int kt = 0; kt < 8; ++kt) {
    int cur = kt & 1;
    if (kt < 7) STAGE(cur ^ 1, (kt + 1) * 64);
    #pragma unroll
    for (int kk = 0; kk < 64; kk += 32) {
      bf16x8s a[4], b[4];
      #pragma unroll
      for (int i = 0; i < 4; ++i) {
        int ra = mh * 64 + i * 16 + fr;
        a[i] = *reinterpret_cast<const bf16x8s*>(
            &lds[cur][0][ra * 128 + ((((kk + ko) >> 3) ^ (ra & 7)) << 4)]);
        int rb = nh * 64 + i * 16 + fr;
        b[i] = *reinterpret_cast<const bf16x8s*>(
            &lds[cur][1][rb * 128 + ((((kk + ko) >> 3) ^ (rb & 7)) << 4)]);
      }
      #pragma unroll
      for (int mi = 0; mi < 4; ++mi)
        #pragma unroll
        for (int ni = 0; ni < 4; ++ni)
          acc[mi][ni] = MFMA(a[mi], b[ni], acc[mi][ni], 0, 0, 0);
    }
    __syncthreads();
  }
  #pragma unroll
  for (int mi = 0; mi < 4; ++mi)
    #pragma unroll
    for (int ni = 0; ni < 4; ++ni)
      #pragma unroll
      for (int j = 0; j < 4; ++j) {
        int row = bm * 128 + mh * 64 + mi * 16 + fq * 4 + j;
        int col = bn * 128 + nh * 64 + ni * 16 + fr;
        float bv = bias ? bias[col] : 0.f;
        outB[(size_t)row * Nld + col] = __float2bfloat16(acc[mi][ni][j] + bv);
      }
}

// ---------------- kfinal: 128x128 tile, K-step 32, 32KB LDS, 4 blocks/CU ----------------
__global__ __launch_bounds__(256, 4) void kfinal(const bf16* __restrict__ Ag,
                                                 const bf16* __restrict__ Bg,
                                                 const float* __restrict__ bias,
                                                 const int* __restrict__ len,
                                                 float* __restrict__ out) {
  __shared__ __align__(16) char lds[2][2][8192];   // [buf][A/B][128 rows x 32 bf16]
  const int nwg = gridDim.x;                       // 5056
  const int bid0 = blockIdx.x;
  const int wg = (bid0 & 7) * (nwg >> 3) + (bid0 >> 3);
  const int bm = wg / 79, bn = wg % 79;
  const int tid = threadIdx.x, w = tid >> 6, lane = tid & 63;
  const int fr = lane & 15, fq = lane >> 4;
  const int mh = w >> 1, nh = w & 1;
  const bf16* Abase = Ag + (size_t)bm * 128 * 512;
  const bf16* Bbase = Bg + (size_t)bn * 128 * 512;
  f32x4 acc[4][4] = {};
  auto STAGE = [&](int buf, int k0) {
    #pragma unroll
    for (int m = 0; m < 2; ++m) {
      const bf16* base = m ? Bbase : Abase;
      #pragma unroll
      for (int it = 0; it < 2; ++it) {
        int u = it * 256 + tid;
        int row = u >> 2, c = u & 3;
        int cs = c ^ ((row >> 1) & 3);
        __builtin_amdgcn_global_load_lds(
          (const __attribute__((address_space(1))) void*)(base + (size_t)row * 512 + k0 + cs * 8),
          (__attribute__((address_space(3))) void*)(&lds[buf][m][((tid & ~63) + it * 256) * 16]),
          16, 0, 0);
      }
    }
  };
  STAGE(0, 0);
  __syncthreads();
  for (int kt = 0; kt < 16; ++kt) {
    int cur = kt & 1;
    if (kt < 15) STAGE(cur ^ 1, (kt + 1) * 32);
    bf16x8s a[4], b[4];
    #pragma unroll
    for (int i = 0; i < 4; ++i) {
      int ra = mh * 64 + i * 16 + fr;
      a[i] = *reinterpret_cast<const bf16x8s*>(
          &lds[cur][0][ra * 64 + ((fq ^ ((ra >> 1) & 3)) << 4)]);
      int rb = nh * 64 + i * 16 + fr;
      b[i] = *reinterpret_cast<const bf16x8s*>(
          &lds[cur][1][rb * 64 + ((fq ^ ((rb >> 1) & 3)) << 4)]);
    }
    #pragma unroll
    for (int mi = 0; mi < 4; ++mi)
      #pragma unroll
      for (int ni = 0; ni < 4; ++ni)
        acc[mi][ni] = MFMA(a[mi], b[ni], acc[mi][ni], 0, 0, 0);
    __syncthreads();
  }
  #pragma unroll
  for (int mi = 0; mi < 4; ++mi)
    #pragma unroll
    for (int ni = 0; ni < 4; ++ni)
      #pragma unroll
      for (int j = 0; j < 4; ++j) {
        int row = bm * 128 + mh * 64 + mi * 16 + fq * 4 + j;
        int col = bn * 128 + nh * 64 + ni * 16 + fr;
        if (col < V) {
          int tt = row >> 7, bb = row & 127;
          out[(size_t)row * V + col] = (tt < len[bb]) ? acc[mi][ni][j] + bias[col] : 0.f;
        }
      }
}

// ---------------- persistent sequential loop, XCD-local, LDS-pinned Kc+Whh ----------------
// 256 blocks launched; first XCD to collect 32 becomes the team; others exit.
// Cross-block data (h, P', Z) T-indexed -> fresh addresses -> shared XCD L2 (r4/r5-proven).
// Barrier: per-block epoch flags via AGENT-scope atomic store/load (r3-proven visible),
// 64-lane parallel poll + ballot -> no serialized RMWs, ~1 MALL RTT per barrier.
__global__ __launch_bounds__(512, 1) void kloop(
    const bf16* __restrict__ Sxb,    // [T][B][512]
    const bf16* __restrict__ Gx,     // [T][B][2048]
    const bf16* __restrict__ Kc,     // [2048][512]
    const bf16* __restrict__ Whh,    // [2048][512]
    const bf16* __restrict__ WaH,    // [512][512]
    const float* __restrict__ gb0,
    const float* __restrict__ gbA,
    const float* __restrict__ cnn,   // [B][512] f32
    const int* __restrict__ len,
    bf16* __restrict__ hstore,       // [T][B][512]
    bf16* __restrict__ pstore,       // [T][B][512]
    float* __restrict__ Zbuf,        // [T][B]
    bf16* __restrict__ hid,          // [T][B][512]
    int* ticket, int* winner, int* flags) {
  __shared__ __align__(16) char KcS[65536];   // [4q][16r][512] chunk-XOR swizzled
  __shared__ __align__(16) char WhS[65536];   // same layout for Whh slice
  __shared__ int steam[2];

  if (threadIdx.x == 0) {
    int xcc;
    asm volatile("s_getreg_b32 %0, hwreg(HW_REG_XCC_ID)" : "=s"(xcc));
    xcc &= 15;
    int my = __hip_atomic_fetch_add(&ticket[xcc], 1, __ATOMIC_RELAXED,
                                    __HIP_MEMORY_SCOPE_AGENT);
    if (my == 31) {
      int exp = -1;
      __hip_atomic_compare_exchange_strong(winner, &exp, xcc, __ATOMIC_RELAXED,
                                           __ATOMIC_RELAXED, __HIP_MEMORY_SCOPE_AGENT);
    }
    int wv;
    while ((wv = __hip_atomic_load(winner, __ATOMIC_RELAXED,
                                   __HIP_MEMORY_SCOPE_AGENT)) < 0)
      __builtin_amdgcn_s_sleep(8);
    steam[0] = (wv == xcc && my < 32) ? 1 : 0;
    steam[1] = my;
  }
  __syncthreads();
  if (!steam[0]) return;
  const int wid = steam[1];

  const int tid = threadIdx.x, w = tid >> 6, lane = tid & 63;
  const int fr = lane & 15, fq = lane >> 4, ko = fq << 3;
  const int cb = wid << 4;              // this block's 16-col slice (att & hidden)
  const int col = cb + fr;

  // preload Kc + Whh slices (64 gate-rows each), chunk-XOR swizzled
  for (int u = tid; u < 4096; u += 512) {
    int row = u >> 6, chunk = u & 63;
    int g = (row >> 4) * 512 + cb + (row & 15);
    int off = row * 1024 + ((chunk ^ (row & 7)) << 4);
    *reinterpret_cast<bf16x8s*>(&KcS[off]) = ld8(Kc + (size_t)g * 512 + chunk * 8);
    *reinterpret_cast<bf16x8s*>(&WhS[off]) = ld8(Whh + (size_t)g * 512 + chunk * 8);
  }

  const int r0 = w * 16 + fq * 4;       // this thread's 4 rows: r0..r0+3
  int4 lv4 = *reinterpret_cast<const int4*>(len + r0);
  int lv[4] = {lv4.x, lv4.y, lv4.z, lv4.w};
  float cnnv[4], gb0v[4], gbAv[4];
  #pragma unroll
  for (int j = 0; j < 4; ++j) cnnv[j] = cnn[(size_t)(r0 + j) * AA + col];
  #pragma unroll
  for (int q = 0; q < 4; ++q) {
    gb0v[q] = gb0[q * 512 + col];
    gbAv[q] = gbA[q * 512 + col];
  }
  float cstv[4] = {0.f, 0.f, 0.f, 0.f};
  u16 hpv[4] = {0, 0, 0, 0};
  __syncthreads();   // LDS ready

  auto arrive = [&](int ep2) {
    __syncthreads();   // drains vmcnt per wave -> prior data stores are in L2
    if (tid == 0)
      __hip_atomic_store(flags + wid * 16, ep2, __ATOMIC_RELAXED,
                         __HIP_MEMORY_SCOPE_AGENT);
  };
  auto wait = [&](int ep2) {
    if (tid < 64) {
      const int* fp = flags + (tid & 31) * 16;
      while (__ballot(__hip_atomic_load(fp, __ATOMIC_RELAXED,
                                        __HIP_MEMORY_SCOPE_AGENT) < ep2))
        __builtin_amdgcn_s_sleep(1);
    }
    __syncthreads();
  };

  int ep = 0;
  for (int t = 0; t < T; ++t) {
    if (t) { ++ep; arrive(ep); }       // A: h[t-1] published
    // ---- prefetch streams (independent of recurrence) ----
    u16 gxv[16];
    u16 sxv[4] = {0, 0, 0, 0};
    #pragma unroll
    for (int q = 0; q < 4; ++q)
      #pragma unroll
      for (int j = 0; j < 4; ++j)
        gxv[q * 4 + j] = __builtin_nontemporal_load(
            (const u16*)Gx + ((size_t)t * B + r0 + j) * 2048 + q * 512 + col);
    if (t) {
      #pragma unroll
      for (int j = 0; j < 4; ++j)
        sxv[j] = __builtin_nontemporal_load(
            (const u16*)Sxb + ((size_t)t * B + r0 + j) * AA + col);
    }
    const bf16* hin = hstore + (size_t)(t ? t - 1 : 0) * B * H;
    bf16* pst = pstore + (size_t)t * B * AA;
    // ---- wait A + phase 1 ----
    if (t) {
      wait(ep);
      f32x4 acc1 = {};
      {
        const bf16* ha = hin + (size_t)(w * 16 + fr) * H + ko;
        const bf16* wb = WaH + (size_t)col * H + ko;
        #pragma unroll 4
        for (int k = 0; k < 512; k += 32)
          acc1 = MFMA(ld8(ha + k), ld8(wb + k), acc1, 0, 0, 0);
      }
      float pj[4];
      #pragma unroll
      for (int j = 0; j < 4; ++j) {
        pj[j] = __expf(acc1[j] + bf2f(sxv[j]));
        bf16 pb = __float2bfloat16(pj[j] * cnnv[j]);
        pst[(size_t)(r0 + j) * AA + col] = pb;
      }
      #pragma unroll
      for (int j = 0; j < 4; ++j) {
        float z = pj[j];
        z += __shfl_xor(z, 1); z += __shfl_xor(z, 2);
        z += __shfl_xor(z, 4); z += __shfl_xor(z, 8);
        if (fr == 0)
          __hip_atomic_fetch_add(Zbuf + t * B + r0 + j, z, __ATOMIC_RELAXED,
                                 __HIP_MEMORY_SCOPE_WORKGROUP);  // RMW in XCD L2
      }
      ++ep; arrive(ep);                // B: P'[t], Z[t] published
    }
    // ---- H-GEMM (overlaps barrier-B propagation) + wait B + P-GEMM ----
    f32x4 accH[4] = {}, accP[4] = {};
    if (t) {
      {
        const bf16* ha = hin + (size_t)(w * 16 + fr) * H + ko;
        #pragma unroll 2
        for (int k = 0; k < 512; k += 32) {
          bf16x8s a = ld8(ha + k);
          #pragma unroll
          for (int q = 0; q < 4; ++q) {
            bf16x8s b = *reinterpret_cast<const bf16x8s*>(
                &WhS[(q * 16 + fr) * 1024 + ((((k >> 3) + fq) ^ (fr & 7)) << 4)]);
            accH[q] = MFMA(a, b, accH[q], 0, 0, 0);
          }
        }
      }
      wait(ep);
      {
        const bf16* pa = pst + (size_t)(w * 16 + fr) * AA + ko;
        #pragma unroll 2
        for (int k = 0; k < 512; k += 32) {
          bf16x8s a = ld8(pa + k);
          #pragma unroll
          for (int q = 0; q < 4; ++q) {
            bf16x8s b = *reinterpret_cast<const bf16x8s*>(
                &KcS[(q * 16 + fr) * 1024 + ((((k >> 3) + fq) ^ (fr & 7)) << 4)]);
            accP[q] = MFMA(a, b, accP[q], 0, 0, 0);
          }
        }
      }
      float4 zv = *reinterpret_cast<const float4*>(Zbuf + t * B + r0);
      float zp[4] = {zv.x, zv.y, zv.z, zv.w};
      #pragma unroll
      for (int q = 0; q < 4; ++q)
        #pragma unroll
        for (int j = 0; j < 4; ++j)
          accP[q][j] *= __fdividef(1.f, zp[j]);
    }
    // ---- gates + cell (all in registers) ----
    float gsel[4];
    #pragma unroll
    for (int q = 0; q < 4; ++q) gsel[q] = t ? gbAv[q] : gb0v[q];
    #pragma unroll
    for (int j = 0; j < 4; ++j) {
      float gi = sigm(accP[0][j] + accH[0][j] + gsel[0] + bf2f(gxv[0 + j]));
      float gf = sigm(accP[1][j] + accH[1][j] + gsel[1] + bf2f(gxv[4 + j]));
      float gg = tanhf(accP[2][j] + accH[2][j] + gsel[2] + bf2f(gxv[8 + j]));
      float go = sigm(accP[3][j] + accH[3][j] + gsel[3] + bf2f(gxv[12 + j]));
      float c2 = gf * cstv[j] + gi * gg;
      float h2 = go * tanhf(c2);
      bool act = t < lv[j];
      if (act) cstv[j] = c2;
      bf16 hb = __float2bfloat16(h2);
      u16 hbits = *reinterpret_cast<u16*>(&hb);
      hpv[j] = act ? hbits : hpv[j];
      ((u16*)hstore)[((size_t)t * B + r0 + j) * H + col] = hpv[j];
      __builtin_nontemporal_store(act ? hbits : (u16)0,
          (u16*)hid + ((size_t)t * B + r0 + j) * H + col);
    }
  }
}

// ---------------- launch ----------------

extern "C" void kernel_launch(void* const* d_in, const int* in_sizes, int n_in,
                              void* d_out, int out_size, void* d_ws, size_t ws_size,
                              hipStream_t stream) {
  const float* feat   = (const float*)d_in[0];
  const int*   cap    = (const int*)d_in[1];
  const int*   len    = (const int*)d_in[2];
  const float* cnn    = (const float*)d_in[3];
  const float* embW   = (const float*)d_in[4];
  const float* Wih_f  = (const float*)d_in[5];
  const float* Whh_f  = (const float*)d_in[6];
  const float* bih    = (const float*)d_in[7];
  const float* bhh    = (const float*)d_in[8];
  const float* attW_f = (const float*)d_in[9];
  const float* attb   = (const float*)d_in[10];
  const float* attdW_f= (const float*)d_in[11];
  const float* attdb  = (const float*)d_in[12];
  const float* outW_f = (const float*)d_in[13];
  const float* outb   = (const float*)d_in[14];
  float* out = (float*)d_out;
  char* ws = (char*)d_ws;

  size_t off = 0;
  auto alloc = [&](size_t n) { char* p = ws + off; off += (n + 255) & ~(size_t)255; return p; };
  bf16*  xs    = (bf16*)alloc(8388608);
  bf16*  WaX   = (bf16*)alloc(524288);
  bf16*  WaH   = (bf16*)alloc(524288);
  bf16*  WdXT  = (bf16*)alloc(524288);
  bf16*  WdAT  = (bf16*)alloc(524288);
  bf16*  Wihb  = (bf16*)alloc(2097152);
  bf16*  Whhb  = (bf16*)alloc(2097152);
  bf16*  Kc    = (bf16*)alloc(2097152);
  bf16*  outWp = (bf16*)alloc(10354688);
  bf16*  Sxb   = (bf16*)alloc(8388608);
  bf16*  Gx    = (bf16*)alloc(33554432);
  bf16*  hid   = (bf16*)alloc(8388608);
  bf16*  hstore= (bf16*)alloc(8388608);
  bf16*  pstore= (bf16*)alloc(8388608);
  float* gb0   = (float*)alloc(8192);
  float* gbA   = (float*)alloc(8192);
  float* Zbuf  = (float*)alloc(32768);
  int*   ticket= (int*)alloc(256);
  int*   winner= (int*)alloc(256);
  int*   flags = (int*)alloc(2048);
  bf16*  Kx    = pstore;   // Kx (2 MB) dead before kloop writes pstore

  kxs<<<4096, 256, 0, stream>>>(feat, cap, embW, xs);
  kslice<<<256, 256, 0, stream>>>(attW_f, WaX, 0);
  kslice<<<256, 256, 0, stream>>>(attW_f, WaH, 512);
  ktrans<<<256, 256, 0, stream>>>(attdW_f, WdXT, 0);
  ktrans<<<256, 256, 0, stream>>>(attdW_f, WdAT, 512);
  kcast<<<1024, 256, 0, stream>>>(Wih_f, Wihb, 262144);
  kcast<<<1024, 256, 0, stream>>>(Whh_f, Whhb, 262144);
  kpadW<<<5056, 256, 0, stream>>>(outW_f, outWp);
  kgb<<<8, 256, 0, stream>>>(bih, bhh, Wih_f, attdb, gb0, gbA);

  // precompute GEMMs (all K=512, A@B^T form)
  kgemm<<<256, 256, 0, stream>>>(xs, WaX, attb, Sxb, 4, 512);
  kgemm<<<64, 256, 0, stream>>>(Wihb, WdXT, nullptr, Kx, 4, 512);
  kgemm<<<64, 256, 0, stream>>>(Wihb, WdAT, nullptr, Kc, 4, 512);
  kgemm<<<1024, 256, 0, stream>>>(xs, Kx, nullptr, Gx, 16, 2048);
  kgemm<<<16, 256, 0, stream>>>(xs, Wihb, nullptr, Gx, 16, 2048); // t=0 rows

  hipMemsetAsync(ticket, 0, 256, stream);
  hipMemsetAsync(winner, 0xFF, 256, stream);   // -1
  hipMemsetAsync(flags, 0, 2048, stream);
  hipMemsetAsync(Zbuf, 0, 32768, stream);

  kloop<<<256, 512, 0, stream>>>(Sxb, Gx, Kc, Whhb, WaH, gb0, gbA, cnn, len,
                                 hstore, pstore, Zbuf, hid, ticket, winner, flags);

  kfinal<<<5056, 256, 0, stream>>>(hid, outWp, outb, len, out);
}